// Round 3
// baseline (332.310 us; speedup 1.0000x reference)
//
#include <hip/hip_runtime.h>
#include <hip/hip_bf16.h>

typedef __attribute__((ext_vector_type(4))) float f32x4;
typedef __attribute__((ext_vector_type(8))) short short8;
typedef __attribute__((ext_vector_type(4))) short short4v;

#define EDIM 512
#define BM 128
#define BN 128
#define BK 64
#define WELEMS 262144  // 512*512

static __device__ __forceinline__ short f2bf(float f) {
  union { float f; unsigned u; } v; v.f = f;
  unsigned r = v.u + 0x7fffu + ((v.u >> 16) & 1u);  // RNE
  return (short)(r >> 16);
}
static __device__ __forceinline__ float bf2f(short s) {
  union { float f; unsigned u; } v; v.u = ((unsigned)(unsigned short)s) << 16;
  return v.f;
}

// async global -> LDS, 16B per lane; lds base wave-uniform + lane*16 linear.
static __device__ __forceinline__ void gload_lds16(const short* g, short* l) {
  __builtin_amdgcn_global_load_lds(
      (const __attribute__((address_space(1))) unsigned int*)g,
      (__attribute__((address_space(3))) unsigned int*)(unsigned int)(unsigned long long)l,
      16, 0, 0);
}

// ---------------- weight fp32 -> bf16 (tiny) ----------------
__global__ __launch_bounds__(256) void convert_w(
    const float* __restrict__ Wq, const float* __restrict__ Wk, const float* __restrict__ Wv,
    short* __restrict__ Wb) {
  int i = (blockIdx.x * 256 + threadIdx.x) * 4;
  f32x4 q = *(const f32x4*)(Wq + i);
  f32x4 k = *(const f32x4*)(Wk + i);
  f32x4 v = *(const f32x4*)(Wv + i);
  short4v qs, ks, vs;
#pragma unroll
  for (int j = 0; j < 4; ++j) { qs[j] = f2bf(q[j]); ks[j] = f2bf(k[j]); vs[j] = f2bf(v[j]); }
  *(short4v*)(Wb + i) = qs;
  *(short4v*)(Wb + WELEMS + i) = ks;
  *(short4v*)(Wb + 2 * WELEMS + i) = vs;
}

// ------- fused projection GEMM: Y = X(fp32)@W^T + b, X converted in staging -------
// 1D grid, mblocks*24 blocks. XCD-aware decode: xcd = L&7 (HW round-robin) owns a
// contiguous m-range; within it, (z,n) iterate innermost so X rows stay L2-resident
// across all 24 uses. z = {q1,k1,v1,q2,k2,v2}.
__global__ __launch_bounds__(256, 3) void proj_gemm(
    const float* __restrict__ X1, const float* __restrict__ X2,
    const short* __restrict__ Wb,
    const float* __restrict__ bq, const float* __restrict__ bk, const float* __restrict__ bv,
    short* __restrict__ QKV, size_t Mc, int mblocks) {
  __shared__ short Al[BM * BK];
  __shared__ short Bl[BN * BK];

  int mb, zn;
  {
    const int L = blockIdx.x;
    if ((mblocks & 7) == 0) {
      const int mpx = mblocks >> 3;       // m-blocks per XCD
      const int xcd = L & 7;
      const int slot = L >> 3;
      mb = xcd * mpx + slot / 24;
      zn = slot % 24;
    } else {
      mb = L / 24; zn = L % 24;
    }
  }
  const int z = zn >> 2;   // 0..5 (4 n-blocks each)
  const int nb = zn & 3;

  const float* __restrict__ X = (z < 3) ? X1 : X2;
  const int wsel = (z < 3) ? z : z - 3;
  const short* __restrict__ W = Wb + wsel * WELEMS;
  const float* __restrict__ bias = (wsel == 0) ? bq : (wsel == 1 ? bk : bv);
  short* __restrict__ O = QKV + (size_t)z * Mc * EDIM;

  const int m0 = mb * BM;
  const int n0 = nb * BN;
  const int tid = threadIdx.x;
  const int lane = tid & 63;
  const int wv = tid >> 6;
  const int wr = wv >> 1, wc = wv & 1;  // 2x2 waves, 64x64 out each
  const int col = lane & 15;
  const int kg = lane >> 4;

  // A staging: 2 threads per row, 4x16B chunks each; swizzled ds_write
  const int arow = tid >> 1;
  const int ahalf = tid & 1;
  const float* Xrow = X + (size_t)(m0 + arow) * EDIM + ahalf * 32;

  f32x4 acc[4][4] = {};

  for (int ks = 0; ks < EDIM / BK; ++ks) {
    const int k0 = ks * BK;
    // A fp32 loads to regs — issued before barrier, overlap prior MFMA phase
    f32x4 a[8];
#pragma unroll
    for (int c = 0; c < 8; ++c) a[c] = *(const f32x4*)(Xrow + k0 + c * 4);
    __syncthreads();  // prior iter's LDS reads complete before overwrite
    // B: async global->LDS, source pre-swizzled (rule #21), linear LDS dest
#pragma unroll
    for (int j = 0; j < 4; ++j) {
      const int g = (j * 4 + wv) * 64 + lane;
      const int row = g >> 3;
      const int sc = (g & 7) ^ (row & 7);
      gload_lds16(W + (size_t)(n0 + row) * EDIM + k0 + sc * 8, Bl + (j * 4 + wv) * 512);
    }
    // A: convert fp32->bf16, swizzled ds_write_b128 (uniform bank spread)
#pragma unroll
    for (int c = 0; c < 4; ++c) {
      short8 w8;
#pragma unroll
      for (int j = 0; j < 4; ++j) { w8[j] = f2bf(a[c * 2][j]); w8[j + 4] = f2bf(a[c * 2 + 1][j]); }
      const int sc = (ahalf * 4 + c) ^ (arow & 7);
      *(short8*)(Al + arow * 64 + sc * 8) = w8;
    }
    __syncthreads();  // drains vmcnt+lgkm
#pragma unroll
    for (int kk = 0; kk < 2; ++kk) {
      short8 af[4], bf8[4];
#pragma unroll
      for (int i = 0; i < 4; ++i) {
        const int ra = wr * 64 + i * 16 + col;
        const int rb = wc * 64 + i * 16 + col;
        af[i]  = *(const short8*)(Al + ra * 64 + ((((kk << 2) + kg) ^ (ra & 7)) << 3));
        bf8[i] = *(const short8*)(Bl + rb * 64 + ((((kk << 2) + kg) ^ (rb & 7)) << 3));
      }
#pragma unroll
      for (int mi = 0; mi < 4; ++mi)
#pragma unroll
        for (int nj = 0; nj < 4; ++nj)
          acc[mi][nj] = __builtin_amdgcn_mfma_f32_16x16x32_bf16(af[mi], bf8[nj], acc[mi][nj], 0, 0, 0);
    }
  }

  // epilogue: C frag row=(lane>>4)*4+j, col=lane&15; add bias; store bf16
#pragma unroll
  for (int nj = 0; nj < 4; ++nj) {
    const int e = n0 + wc * 64 + nj * 16 + col;
    const float bb = bias[e];
#pragma unroll
    for (int mi = 0; mi < 4; ++mi) {
      const size_t mbrow = m0 + wr * 64 + mi * 16 + kg * 4;
#pragma unroll
      for (int j = 0; j < 4; ++j)
        O[(mbrow + j) * EDIM + e] = f2bf(acc[mi][nj][j] + bb);
    }
  }
}

// ---------------- block attention: one wave per 16-row block, both dirs ------
__global__ __launch_bounds__(256) void attn_kernel(
    const short* __restrict__ QKV, float* __restrict__ out1, float* __restrict__ out2,
    size_t Mc) {
  __shared__ float plds[4][16][16];
  const int dir = blockIdx.y;
  const size_t sz = Mc * EDIM;
  const short* __restrict__ Q = QKV + (dir ? 3 : 0) * sz;
  const short* __restrict__ K = QKV + (dir ? 1 : 4) * sz;
  const short* __restrict__ V = QKV + (dir ? 2 : 5) * sz;
  float* __restrict__ O = dir ? out2 : out1;

  const int lane = threadIdx.x & 63;
  const int wv = threadIdx.x >> 6;
  const size_t r0 = ((size_t)blockIdx.x * 4 + wv) * 16;
  const int col = lane & 15;
  const int kg = lane >> 4;

  const short* Qp = Q + (r0 + col) * EDIM + kg * 8;
  const short* Kp = K + (r0 + col) * EDIM + kg * 8;
  f32x4 s = {};
#pragma unroll
  for (int ks = 0; ks < 16; ++ks) {
    short8 a = *(const short8*)(Qp + ks * 32);
    short8 b = *(const short8*)(Kp + ks * 32);
    s = __builtin_amdgcn_mfma_f32_16x16x32_bf16(a, b, s, 0, 0, 0);
  }
  const float scale = 0.04419417382415922f;  // 1/sqrt(512)
  float p[4];
#pragma unroll
  for (int j = 0; j < 4; ++j) p[j] = s[j] * scale;
#pragma unroll
  for (int j = 0; j < 4; ++j) {
    float m = p[j];
#pragma unroll
    for (int d = 1; d < 16; d <<= 1) m = fmaxf(m, __shfl_xor(m, d));
    float e = __expf(p[j] - m);
    float ssum = e;
#pragma unroll
    for (int d = 1; d < 16; d <<= 1) ssum += __shfl_xor(ssum, d);
    p[j] = e / ssum;
  }
#pragma unroll
  for (int j = 0; j < 4; ++j) plds[wv][kg * 4 + j][col] = p[j];
  __syncthreads();

  const int e0 = lane * 8;
  short8 v8[16];
#pragma unroll
  for (int k = 0; k < 16; ++k) v8[k] = *(const short8*)(V + (r0 + k) * EDIM + e0);
#pragma unroll
  for (int q = 0; q < 16; ++q) {
    float acc[8] = {0, 0, 0, 0, 0, 0, 0, 0};
#pragma unroll
    for (int k = 0; k < 16; ++k) {
      const float pv = plds[wv][q][k];
#pragma unroll
      for (int i = 0; i < 8; ++i) acc[i] += pv * bf2f(v8[k][i]);
    }
    f32x4 o0 = {acc[0], acc[1], acc[2], acc[3]};
    f32x4 o1 = {acc[4], acc[5], acc[6], acc[7]};
    *(f32x4*)(O + (r0 + q) * EDIM + e0) = o0;
    *(f32x4*)(O + (r0 + q) * EDIM + e0 + 4) = o1;
  }
}

// ---------------- host ----------------
extern "C" void kernel_launch(void* const* d_in, const int* in_sizes, int n_in,
                              void* d_out, int out_size, void* d_ws, size_t ws_size,
                              hipStream_t stream) {
  const float* state1 = (const float*)d_in[0];
  const float* state2 = (const float*)d_in[1];
  const float* Wq = (const float*)d_in[2];
  const float* bq = (const float*)d_in[3];
  const float* Wk = (const float*)d_in[4];
  const float* bk = (const float*)d_in[5];
  const float* Wv = (const float*)d_in[6];
  const float* bv = (const float*)d_in[7];

  const size_t Mtot = (size_t)8 * 4096;
  float* out1 = (float*)d_out;
  float* out2 = out1 + Mtot * EDIM;

  short* Wb = (short*)d_ws;  // 3 * 512*512 bf16 = 1.5 MB
  short* QKVbase = Wb + 3 * WELEMS;

  // chunk M so 6 QKV bf16 buffers fit in ws
  size_t nch = 1;
  while (nch < 256) {
    size_t need = ((size_t)3 * WELEMS + 6 * (Mtot / nch) * EDIM) * sizeof(short);
    if (need <= ws_size) break;
    nch <<= 1;
  }
  const size_t Mc = Mtot / nch;
  const int mblocks = (int)(Mc / BM);
  short* QKV = QKVbase;

  convert_w<<<dim3(256), dim3(256), 0, stream>>>(Wq, Wk, Wv, Wb);

  for (size_t c = 0; c < nch; ++c) {
    const size_t roff = c * Mc;
    proj_gemm<<<dim3((unsigned)(mblocks * 24)), dim3(256), 0, stream>>>(
        state1 + roff * EDIM, state2 + roff * EDIM, Wb, bq, bk, bv, QKV, Mc, mblocks);
    attn_kernel<<<dim3((unsigned)(Mc / 64), 2), dim3(256), 0, stream>>>(
        QKV, out1 + roff * EDIM, out2 + roff * EDIM, Mc);
  }
}

// Round 4
// 280.045 us; speedup vs baseline: 1.1866x; 1.1866x over previous
//
#include <hip/hip_runtime.h>
#include <hip/hip_bf16.h>

typedef __attribute__((ext_vector_type(4))) float f32x4;
typedef __attribute__((ext_vector_type(8))) short short8;
typedef __attribute__((ext_vector_type(4))) short short4v;

#define EDIM 512
#define WELEMS 262144  // 512*512

static __device__ __forceinline__ short f2bf(float f) {
  union { float f; unsigned u; } v; v.f = f;
  unsigned r = v.u + 0x7fffu + ((v.u >> 16) & 1u);  // RNE
  return (short)(r >> 16);
}
static __device__ __forceinline__ float bf2f(short s) {
  union { float f; unsigned u; } v; v.u = ((unsigned)(unsigned short)s) << 16;
  return v.f;
}

// async global -> LDS, 16B per lane; lds base wave-uniform + lane*16 linear.
static __device__ __forceinline__ void gload_lds16(const short* g, short* l) {
  __builtin_amdgcn_global_load_lds(
      (const __attribute__((address_space(1))) unsigned int*)g,
      (__attribute__((address_space(3))) unsigned int*)(unsigned int)(unsigned long long)l,
      16, 0, 0);
}

// ---------------- weight fp32 -> bf16 (tiny) ----------------
__global__ __launch_bounds__(256) void convert_w(
    const float* __restrict__ Wq, const float* __restrict__ Wk, const float* __restrict__ Wv,
    short* __restrict__ Wb) {
  int i = (blockIdx.x * 256 + threadIdx.x) * 4;
  f32x4 q = *(const f32x4*)(Wq + i);
  f32x4 k = *(const f32x4*)(Wk + i);
  f32x4 v = *(const f32x4*)(Wv + i);
  short4v qs, ks, vs;
#pragma unroll
  for (int j = 0; j < 4; ++j) { qs[j] = f2bf(q[j]); ks[j] = f2bf(k[j]); vs[j] = f2bf(v[j]); }
  *(short4v*)(Wb + i) = qs;
  *(short4v*)(Wb + WELEMS + i) = ks;
  *(short4v*)(Wb + 2 * WELEMS + i) = vs;
}

// ---------------- states fp32 -> bf16 ----------------
__global__ __launch_bounds__(256) void convert_x(
    const float* __restrict__ s1, const float* __restrict__ s2,
    short* __restrict__ o1, short* __restrict__ o2) {
  const long e = ((long)blockIdx.x * 256 + threadIdx.x) * 8;
  f32x4 a0 = *(const f32x4*)(s1 + e), a1 = *(const f32x4*)(s1 + e + 4);
  f32x4 b0 = *(const f32x4*)(s2 + e), b1 = *(const f32x4*)(s2 + e + 4);
  short8 r1, r2;
#pragma unroll
  for (int j = 0; j < 4; ++j) {
    r1[j] = f2bf(a0[j]); r1[j + 4] = f2bf(a1[j]);
    r2[j] = f2bf(b0[j]); r2[j + 4] = f2bf(b1[j]);
  }
  *(short8*)(o1 + e) = r1;
  *(short8*)(o2 + e) = r2;
}

// ------- projection GEMM, 256x256 tile, 8 waves, 8-phase counted-vmcnt schedule -
// Y = X @ W^T + b. grid = mtiles*12 (6z x 2nb per m-tile), XCD-aware decode.
// LDS: [buf(2)][mat A/B(2)][khalf(2)] x (256 rows x 32 bf16) = 128 KiB.
// Half-tile = one (mat,khalf) = 16KB = 512 thr x 2 gload_lds. Swizzle: within a
// 64B row of 4 chunks, chunk c stored at c ^ ((row>>1)&3) (inverse-swz source,
// swz read: rule #21). Stage at phase p overwrites the region consumed at p-1
// (reads completed by p-1's lgkmcnt(0) + trailing barrier) -> race-free.
// vmcnt(6) = 3 half-tiles in flight, waited only at phases 4 and 8.
__global__ __launch_bounds__(512, 2) void proj_gemm(
    const short* __restrict__ S1b, const short* __restrict__ S2b,
    const short* __restrict__ Wb,
    const float* __restrict__ bq, const float* __restrict__ bk, const float* __restrict__ bv,
    short* __restrict__ QKV, size_t Mc, int mtiles) {
  __shared__ short lds[8][8192];

  int mb, zn;
  {
    const int L = blockIdx.x;
    if ((mtiles & 7) == 0) {
      const int mpx = mtiles >> 3;
      const int xcd = L & 7;
      const int slot = L >> 3;
      mb = xcd * mpx + slot / 12;
      zn = slot % 12;
    } else { mb = L / 12; zn = L % 12; }
  }
  const int z = zn >> 1;   // 0..5 = {q1,k1,v1,q2,k2,v2}
  const int nb = zn & 1;

  const short* __restrict__ X = (z < 3) ? S1b : S2b;
  const int wsel = (z < 3) ? z : z - 3;
  const short* __restrict__ W = Wb + wsel * WELEMS;
  const float* __restrict__ bias = (wsel == 0) ? bq : (wsel == 1 ? bk : bv);
  short* __restrict__ O = QKV + (size_t)z * Mc * EDIM;

  const int m0 = mb * 256;
  const int n0 = nb * 256;
  const int tid = threadIdx.x;
  const int lane = tid & 63;
  const int wv = tid >> 6;    // 0..7
  const int wr = wv >> 2;     // M-half of block (128 rows)
  const int wc = wv & 3;      // N-quarter (64 cols)
  const int col = lane & 15;
  const int kg = lane >> 4;

  const short* __restrict__ Abase = X + (size_t)m0 * EDIM;
  const short* __restrict__ Bbase = W + (size_t)n0 * EDIM;

  // stage one half-tile: stream position pos -> (tile, part)
  auto STAGE = [&](int pos) {
    const int tile = pos >> 2;
    const int t = tile > 7 ? 7 : tile;      // tail clamp (slot timing stays valid)
    const int part = pos & 3;               // 0:A.kh0 1:B.kh0 2:A.kh1 3:B.kh1
    const int mat = part & 1;
    const int kh = part >> 1;
    const int slot = ((tile & 1) * 2 + mat) * 2 + kh;
    const short* src = mat ? Bbase : Abase;
    const int kbase = t * 64 + kh * 32;
#pragma unroll
    for (int q = 0; q < 2; ++q) {
      const int g = (q * 8 + wv) * 64 + lane;
      const int row = g >> 2;
      const int c = g & 3;
      const int cs = c ^ ((row >> 1) & 3);
      gload_lds16(src + (size_t)row * EDIM + kbase + cs * 8,
                  &lds[slot][(q * 8 + wv) * 512]);
    }
  };

  f32x4 acc[8][4] = {};
  short8 bfr[4];

#define PH(BUFB, KH, MH, RELB, POS, WAIT6)                                     \
  {                                                                            \
    const short* Ar = &lds[(BUFB) * 4 + (KH)][0];                              \
    const short* Br = &lds[(BUFB) * 4 + 2 + (KH)][0];                          \
    short8 af[4];                                                              \
    _Pragma("unroll") for (int i = 0; i < 4; ++i) {                            \
      const int ra = wr * 128 + (MH) * 64 + i * 16 + col;                      \
      af[i] = *(const short8*)(Ar + ra * 32 + ((kg ^ ((ra >> 1) & 3)) << 3));  \
    }                                                                          \
    if (RELB) {                                                                \
      _Pragma("unroll") for (int j = 0; j < 4; ++j) {                          \
        const int rb = wc * 64 + j * 16 + col;                                 \
        bfr[j] = *(const short8*)(Br + rb * 32 + ((kg ^ ((rb >> 1) & 3)) << 3)); \
      }                                                                        \
    }                                                                          \
    STAGE(POS);                                                                \
    __builtin_amdgcn_s_barrier();                                              \
    asm volatile("s_waitcnt lgkmcnt(0)" ::: "memory");                         \
    __builtin_amdgcn_s_setprio(1);                                             \
    _Pragma("unroll") for (int mi = 0; mi < 4; ++mi)                           \
      _Pragma("unroll") for (int nj = 0; nj < 4; ++nj)                         \
        acc[(MH) * 4 + mi][nj] = __builtin_amdgcn_mfma_f32_16x16x32_bf16(      \
            af[mi], bfr[nj], acc[(MH) * 4 + mi][nj], 0, 0, 0);                 \
    __builtin_amdgcn_s_setprio(0);                                             \
    if (WAIT6) asm volatile("s_waitcnt vmcnt(6)" ::: "memory");                \
    __builtin_amdgcn_s_barrier();                                              \
  }

  // prologue: tile0 (4 half-tiles), wait first 2 landed; +3 of tile1, keep 3 in flight
  STAGE(0); STAGE(1); STAGE(2); STAGE(3);
  asm volatile("s_waitcnt vmcnt(4)" ::: "memory");
  STAGE(4); STAGE(5); STAGE(6);
  asm volatile("s_waitcnt vmcnt(6)" ::: "memory");
  __builtin_amdgcn_s_barrier();

#pragma unroll
  for (int it = 0; it < 4; ++it) {
    const int s0 = 7 + it * 8;
    PH(0, 0, 0, 1, s0 + 0, 0)
    PH(0, 0, 1, 0, s0 + 1, 0)
    PH(0, 1, 0, 1, s0 + 2, 0)
    PH(0, 1, 1, 0, s0 + 3, 1)
    PH(1, 0, 0, 1, s0 + 4, 0)
    PH(1, 0, 1, 0, s0 + 5, 0)
    PH(1, 1, 0, 1, s0 + 6, 0)
    PH(1, 1, 1, 0, s0 + 7, 1)
  }
#undef PH

  // epilogue: C frag row=(lane>>4)*4+j, col=lane&15; add bias; store bf16
#pragma unroll
  for (int nj = 0; nj < 4; ++nj) {
    const int e = n0 + wc * 64 + nj * 16 + col;
    const float bb = bias[e];
#pragma unroll
    for (int mi = 0; mi < 8; ++mi) {
      const size_t r = m0 + wr * 128 + mi * 16 + kg * 4;
#pragma unroll
      for (int j = 0; j < 4; ++j)
        O[(r + j) * EDIM + e] = f2bf(acc[mi][nj][j] + bb);
    }
  }
}

// ---------------- block attention: one wave per 16-row block, both dirs ------
__global__ __launch_bounds__(256) void attn_kernel(
    const short* __restrict__ QKV, float* __restrict__ out1, float* __restrict__ out2,
    size_t Mc) {
  __shared__ float plds[4][16][16];
  const int dir = blockIdx.y;
  const size_t sz = Mc * EDIM;
  const short* __restrict__ Q = QKV + (dir ? 3 : 0) * sz;
  const short* __restrict__ K = QKV + (dir ? 1 : 4) * sz;
  const short* __restrict__ V = QKV + (dir ? 2 : 5) * sz;
  float* __restrict__ O = dir ? out2 : out1;

  const int lane = threadIdx.x & 63;
  const int wv = threadIdx.x >> 6;
  const size_t r0 = ((size_t)blockIdx.x * 4 + wv) * 16;
  const int col = lane & 15;
  const int kg = lane >> 4;

  const short* Qp = Q + (r0 + col) * EDIM + kg * 8;
  const short* Kp = K + (r0 + col) * EDIM + kg * 8;
  f32x4 s = {};
#pragma unroll
  for (int ks = 0; ks < 16; ++ks) {
    short8 a = *(const short8*)(Qp + ks * 32);
    short8 b = *(const short8*)(Kp + ks * 32);
    s = __builtin_amdgcn_mfma_f32_16x16x32_bf16(a, b, s, 0, 0, 0);
  }
  const float scale = 0.04419417382415922f;  // 1/sqrt(512)
  float p[4];
#pragma unroll
  for (int j = 0; j < 4; ++j) p[j] = s[j] * scale;
#pragma unroll
  for (int j = 0; j < 4; ++j) {
    float m = p[j];
#pragma unroll
    for (int d = 1; d < 16; d <<= 1) m = fmaxf(m, __shfl_xor(m, d));
    float e = __expf(p[j] - m);
    float ssum = e;
#pragma unroll
    for (int d = 1; d < 16; d <<= 1) ssum += __shfl_xor(ssum, d);
    p[j] = e / ssum;
  }
#pragma unroll
  for (int j = 0; j < 4; ++j) plds[wv][kg * 4 + j][col] = p[j];
  __syncthreads();

  const int e0 = lane * 8;
  short8 v8[16];
#pragma unroll
  for (int k = 0; k < 16; ++k) v8[k] = *(const short8*)(V + (r0 + k) * EDIM + e0);
#pragma unroll
  for (int q = 0; q < 16; ++q) {
    float acc[8] = {0, 0, 0, 0, 0, 0, 0, 0};
#pragma unroll
    for (int k = 0; k < 16; ++k) {
      const float pv = plds[wv][q][k];
#pragma unroll
      for (int i = 0; i < 8; ++i) acc[i] += pv * bf2f(v8[k][i]);
    }
    f32x4 o0 = {acc[0], acc[1], acc[2], acc[3]};
    f32x4 o1 = {acc[4], acc[5], acc[6], acc[7]};
    *(f32x4*)(O + (r0 + q) * EDIM + e0) = o0;
    *(f32x4*)(O + (r0 + q) * EDIM + e0 + 4) = o1;
  }
}

// ---------------- host ----------------
extern "C" void kernel_launch(void* const* d_in, const int* in_sizes, int n_in,
                              void* d_out, int out_size, void* d_ws, size_t ws_size,
                              hipStream_t stream) {
  const float* state1 = (const float*)d_in[0];
  const float* state2 = (const float*)d_in[1];
  const float* Wq = (const float*)d_in[2];
  const float* bq = (const float*)d_in[3];
  const float* Wk = (const float*)d_in[4];
  const float* bk = (const float*)d_in[5];
  const float* Wv = (const float*)d_in[6];
  const float* bv = (const float*)d_in[7];

  const size_t Mtot = (size_t)8 * 4096;
  float* out1 = (float*)d_out;
  float* out2 = out1 + Mtot * EDIM;

  short* Wb = (short*)d_ws;  // 3 * 512*512 bf16 = 1.5 MB
  short* base = Wb + 3 * WELEMS;

  // chunk M so {2 state chunks + 6 QKV chunks} bf16 fit in ws
  size_t nch = 1;
  while (nch < 256) {
    size_t need = ((size_t)3 * WELEMS + 8 * (Mtot / nch) * EDIM) * sizeof(short);
    if (need <= ws_size) break;
    nch <<= 1;
  }
  const size_t Mc = Mtot / nch;
  const int mtiles = (int)(Mc / 256);
  short* S1b = base;
  short* S2b = S1b + Mc * EDIM;
  short* QKV = S2b + Mc * EDIM;

  convert_w<<<dim3(256), dim3(256), 0, stream>>>(Wq, Wk, Wv, Wb);

  for (size_t c = 0; c < nch; ++c) {
    const size_t roff = c * Mc;
    convert_x<<<dim3((unsigned)(Mc / 4)), dim3(256), 0, stream>>>(
        state1 + roff * EDIM, state2 + roff * EDIM, S1b, S2b);
    proj_gemm<<<dim3((unsigned)(mtiles * 12)), dim3(512), 0, stream>>>(
        S1b, S2b, Wb, bq, bk, bv, QKV, Mc, mtiles);
    attn_kernel<<<dim3((unsigned)(Mc / 64), 2), dim3(256), 0, stream>>>(
        QKV, out1 + roff * EDIM, out2 + roff * EDIM, Mc);
  }
}

// Round 5
// 272.738 us; speedup vs baseline: 1.2184x; 1.0268x over previous
//
#include <hip/hip_runtime.h>
#include <hip/hip_bf16.h>

typedef __attribute__((ext_vector_type(4))) float f32x4;
typedef __attribute__((ext_vector_type(8))) short short8;
typedef __attribute__((ext_vector_type(4))) short short4v;

#define EDIM 512
#define WELEMS 262144  // 512*512

static __device__ __forceinline__ short f2bf(float f) {
  union { float f; unsigned u; } v; v.f = f;
  unsigned r = v.u + 0x7fffu + ((v.u >> 16) & 1u);  // RNE
  return (short)(r >> 16);
}
static __device__ __forceinline__ float bf2f(short s) {
  union { float f; unsigned u; } v; v.u = ((unsigned)(unsigned short)s) << 16;
  return v.f;
}

// async global -> LDS, 16B per lane; lds base wave-uniform + lane*16 linear.
static __device__ __forceinline__ void gload_lds16(const short* g, short* l) {
  __builtin_amdgcn_global_load_lds(
      (const __attribute__((address_space(1))) unsigned int*)g,
      (__attribute__((address_space(3))) unsigned int*)(unsigned int)(unsigned long long)l,
      16, 0, 0);
}

// ---------------- Wv fp32 -> bf16 (tiny) ----------------
__global__ __launch_bounds__(256) void convert_wv(
    const float* __restrict__ Wv, short* __restrict__ Wvb) {
  int i = (blockIdx.x * 256 + threadIdx.x) * 4;
  f32x4 v = *(const f32x4*)(Wv + i);
  short4v vs;
#pragma unroll
  for (int j = 0; j < 4; ++j) vs[j] = f2bf(v[j]);
  *(short4v*)(Wvb + i) = vs;
}

// ---------------- tvec = Wk^T @ bq (512-vec, fp32) ----------------
__global__ __launch_bounds__(256) void compute_tvec(
    const float* __restrict__ Wk, const float* __restrict__ bq, float* __restrict__ tvec) {
  const int f = blockIdx.x * 256 + threadIdx.x;
  float s = 0.f;
  for (int n = 0; n < EDIM; ++n) s += Wk[n * EDIM + f] * bq[n];  // coalesced over f
  tvec[f] = s;
}

// ---------------- H[f][e] = sum_n Wk[n,f] * Wq[n,e]  (bf16 out) ----------------
// grid 64 blocks (8x8 tiles of 64x64); fp32 accumulate from fp32 weights.
__global__ __launch_bounds__(256) void compute_h(
    const float* __restrict__ Wq, const float* __restrict__ Wk, short* __restrict__ H) {
  __shared__ float Kt[64][65];
  __shared__ float Qt[64][65];
  const int bf = (blockIdx.x >> 3) * 64;
  const int be = (blockIdx.x & 7) * 64;
  const int tid = threadIdx.x;
  const int lc = tid & 63, lr = tid >> 6;  // load: 64 cols x 4 rows per pass
  const int fh = (tid & 15) * 4, eh = (tid >> 4) * 4;
  float acc[4][4] = {};
  for (int nc = 0; nc < 8; ++nc) {
    __syncthreads();
#pragma unroll
    for (int p = 0; p < 16; ++p) {
      const int n = p * 4 + lr;
      Kt[n][lc] = Wk[(size_t)(nc * 64 + n) * EDIM + bf + lc];
      Qt[n][lc] = Wq[(size_t)(nc * 64 + n) * EDIM + be + lc];
    }
    __syncthreads();
    for (int n = 0; n < 64; ++n) {
      float kv[4], qv[4];
#pragma unroll
      for (int i = 0; i < 4; ++i) { kv[i] = Kt[n][fh + i]; qv[i] = Qt[n][eh + i]; }
#pragma unroll
      for (int i = 0; i < 4; ++i)
#pragma unroll
        for (int j = 0; j < 4; ++j) acc[i][j] += kv[i] * qv[j];
    }
  }
#pragma unroll
  for (int i = 0; i < 4; ++i)
#pragma unroll
    for (int j = 0; j < 4; ++j)
      H[(size_t)(bf + fh + i) * EDIM + be + eh + j] = f2bf(acc[i][j]);
}

// ------- states fp32 -> bf16 + w = X @ tvec (one wave per row) -------
__global__ __launch_bounds__(256) void convert_x(
    const float* __restrict__ s1, const float* __restrict__ s2,
    const float* __restrict__ tvec,
    short* __restrict__ o1, short* __restrict__ o2,
    float* __restrict__ w1, float* __restrict__ w2) {
  const int wv = threadIdx.x >> 6, lane = threadIdx.x & 63;
  const size_t r = (size_t)blockIdx.x * 4 + wv;
  const int off = lane * 8;
  const f32x4 t0 = *(const f32x4*)(tvec + off);
  const f32x4 t1 = *(const f32x4*)(tvec + off + 4);
#pragma unroll
  for (int st = 0; st < 2; ++st) {
    const float* src = st ? s2 : s1;
    f32x4 a0 = *(const f32x4*)(src + r * EDIM + off);
    f32x4 a1 = *(const f32x4*)(src + r * EDIM + off + 4);
    short8 rb;
    float dot = 0.f;
#pragma unroll
    for (int j = 0; j < 4; ++j) {
      rb[j] = f2bf(a0[j]); dot += a0[j] * t0[j];
      rb[j + 4] = f2bf(a1[j]); dot += a1[j] * t1[j];
    }
    *(short8*)((st ? o2 : o1) + r * EDIM + off) = rb;
#pragma unroll
    for (int d = 1; d < 64; d <<= 1) dot += __shfl_xor(dot, d);
    if (lane == 0) (st ? w2 : w1)[r] = dot;
  }
}

// ------- projection GEMM (r2 structure): out = X @ W^T (+ bv for V slices) -------
// grid = mblocks*16, XCD decode. zn: z=zn>>2 in {T1,T2,V1,V2}, nb=zn&3.
// LDS linear, source pre-swizzled chunk^=(row&7); swizzled ds_read (rule #21).
__global__ __launch_bounds__(256, 3) void proj_gemm(
    const short* __restrict__ S1b, const short* __restrict__ S2b,
    const short* __restrict__ Hb, const short* __restrict__ Wvb,
    const float* __restrict__ bv,
    short* __restrict__ TV, size_t McE, int mblocks) {
  __shared__ short Al[128 * 64];
  __shared__ short Bl[128 * 64];

  int mb, zn;
  {
    const int L = blockIdx.x;
    if ((mblocks & 7) == 0) {
      const int mpx = mblocks >> 3;
      const int xcd = L & 7;
      const int slot = L >> 3;
      mb = xcd * mpx + slot / 16;
      zn = slot % 16;
    } else { mb = L / 16; zn = L % 16; }
  }
  const int z = zn >> 2;   // 0:T1 1:T2 2:V1 3:V2
  const int nb = zn & 3;

  const short* __restrict__ X = (z & 1) ? S2b : S1b;
  const short* __restrict__ W = (z < 2) ? Hb : Wvb;
  short* __restrict__ O = TV + (size_t)z * McE;

  const int m0 = mb * 128;
  const int n0 = nb * 128;
  const int tid = threadIdx.x;
  const int lane = tid & 63;
  const int wv = tid >> 6;
  const int wr = wv >> 1, wc = wv & 1;  // 2x2 waves, 64x64 out each
  const int col = lane & 15;
  const int kg = lane >> 4;

  f32x4 acc[4][4] = {};

  for (int ks = 0; ks < EDIM / 64; ++ks) {
    const int k0 = ks * 64;
    __syncthreads();
#pragma unroll
    for (int j = 0; j < 4; ++j) {
      const int g = (j * 4 + wv) * 64 + lane;
      const int row = g >> 3;
      const int sc = (g & 7) ^ (row & 7);
      gload_lds16(X + (size_t)(m0 + row) * EDIM + k0 + sc * 8, Al + (j * 4 + wv) * 512);
      gload_lds16(W + (size_t)(n0 + row) * EDIM + k0 + sc * 8, Bl + (j * 4 + wv) * 512);
    }
    __syncthreads();
#pragma unroll
    for (int kk = 0; kk < 2; ++kk) {
      short8 af[4], bf8[4];
#pragma unroll
      for (int i = 0; i < 4; ++i) {
        const int ra = wr * 64 + i * 16 + col;
        const int rb = wc * 64 + i * 16 + col;
        af[i]  = *(const short8*)(Al + ra * 64 + ((((kk << 2) + kg) ^ (ra & 7)) << 3));
        bf8[i] = *(const short8*)(Bl + rb * 64 + ((((kk << 2) + kg) ^ (rb & 7)) << 3));
      }
#pragma unroll
      for (int mi = 0; mi < 4; ++mi)
#pragma unroll
        for (int nj = 0; nj < 4; ++nj)
          acc[mi][nj] = __builtin_amdgcn_mfma_f32_16x16x32_bf16(af[mi], bf8[nj], acc[mi][nj], 0, 0, 0);
    }
  }

  // epilogue: row-major store order (consecutive nj -> contiguous 128B per row)
#pragma unroll
  for (int mi = 0; mi < 4; ++mi) {
#pragma unroll
    for (int j = 0; j < 4; ++j) {
      const size_t r = m0 + wr * 64 + mi * 16 + kg * 4 + j;
#pragma unroll
      for (int nj = 0; nj < 4; ++nj) {
        const int e = n0 + wc * 64 + nj * 16 + col;
        const float bb = (z < 2) ? 0.f : bv[e];
        O[r * EDIM + e] = f2bf(acc[mi][nj][j] + bb);
      }
    }
  }
}

// ------- block attention: S = T@X^T + w[j]; softmax; @V. one wave per 16-row block --
__global__ __launch_bounds__(256) void attn_kernel(
    const short* __restrict__ TV, const short* __restrict__ S1b, const short* __restrict__ S2b,
    const float* __restrict__ w1, const float* __restrict__ w2,
    float* __restrict__ out1, float* __restrict__ out2, size_t McE) {
  __shared__ float plds[4][16][16];
  const int dir = blockIdx.y;
  const short* __restrict__ Q = TV + (dir ? McE : 0);          // T2 : T1
  const short* __restrict__ K = dir ? S1b : S2b;
  const short* __restrict__ V = TV + (dir ? 2 : 3) * McE;      // V1 : V2
  const float* __restrict__ w = dir ? w1 : w2;
  float* __restrict__ O = dir ? out2 : out1;

  const int lane = threadIdx.x & 63;
  const int wv = threadIdx.x >> 6;
  const size_t r0 = ((size_t)blockIdx.x * 4 + wv) * 16;
  const int col = lane & 15;
  const int kg = lane >> 4;

  const short* Qp = Q + (r0 + col) * EDIM + kg * 8;
  const short* Kp = K + (r0 + col) * EDIM + kg * 8;
  f32x4 s = {};
#pragma unroll
  for (int ks = 0; ks < 16; ++ks) {
    short8 a = *(const short8*)(Qp + ks * 32);
    short8 b = *(const short8*)(Kp + ks * 32);
    s = __builtin_amdgcn_mfma_f32_16x16x32_bf16(a, b, s, 0, 0, 0);
  }
  const float scale = 0.04419417382415922f;  // 1/sqrt(512)
  const float wj = w[r0 + col];              // per-k-column bias term
  float p[4];
#pragma unroll
  for (int j = 0; j < 4; ++j) p[j] = (s[j] + wj) * scale;
#pragma unroll
  for (int j = 0; j < 4; ++j) {
    float m = p[j];
#pragma unroll
    for (int d = 1; d < 16; d <<= 1) m = fmaxf(m, __shfl_xor(m, d));
    float e = __expf(p[j] - m);
    float ssum = e;
#pragma unroll
    for (int d = 1; d < 16; d <<= 1) ssum += __shfl_xor(ssum, d);
    p[j] = e / ssum;
  }
#pragma unroll
  for (int j = 0; j < 4; ++j) plds[wv][kg * 4 + j][col] = p[j];
  __syncthreads();

  const int e0 = lane * 8;
  short8 v8[16];
#pragma unroll
  for (int k = 0; k < 16; ++k) v8[k] = *(const short8*)(V + (r0 + k) * EDIM + e0);
#pragma unroll
  for (int q = 0; q < 16; ++q) {
    float acc[8] = {0, 0, 0, 0, 0, 0, 0, 0};
#pragma unroll
    for (int k = 0; k < 16; ++k) {
      const float pv = plds[wv][q][k];
#pragma unroll
      for (int i = 0; i < 8; ++i) acc[i] += pv * bf2f(v8[k][i]);
    }
    f32x4 o0 = {acc[0], acc[1], acc[2], acc[3]};
    f32x4 o1 = {acc[4], acc[5], acc[6], acc[7]};
    *(f32x4*)(O + (r0 + q) * EDIM + e0) = o0;
    *(f32x4*)(O + (r0 + q) * EDIM + e0 + 4) = o1;
  }
}

// ---------------- host ----------------
extern "C" void kernel_launch(void* const* d_in, const int* in_sizes, int n_in,
                              void* d_out, int out_size, void* d_ws, size_t ws_size,
                              hipStream_t stream) {
  const float* state1 = (const float*)d_in[0];
  const float* state2 = (const float*)d_in[1];
  const float* Wq = (const float*)d_in[2];
  const float* bq = (const float*)d_in[3];
  const float* Wk = (const float*)d_in[4];
  // d_in[5] = bk: only enters via softmax-invariant terms -> unused
  const float* Wv = (const float*)d_in[6];
  const float* bv = (const float*)d_in[7];

  const size_t Mtot = (size_t)8 * 4096;
  float* out1 = (float*)d_out;
  float* out2 = out1 + Mtot * EDIM;

  // ws layout: Wvb | Hb | tvec | w1 | w2 | per-chunk {S1b, S2b, TV[4]}
  short* Wvb = (short*)d_ws;
  short* Hb = Wvb + WELEMS;
  float* tvec = (float*)(Hb + WELEMS);
  float* w1 = tvec + EDIM;
  float* w2 = w1 + Mtot;
  short* base = (short*)(w2 + Mtot);

  const size_t fixed_bytes = (size_t)(2 * WELEMS) * 2 + (EDIM + 2 * Mtot) * 4;
  size_t nch = 1;
  while (nch < 256) {
    size_t need = fixed_bytes + (size_t)6 * (Mtot / nch) * EDIM * 2;
    if (need <= ws_size) break;
    nch <<= 1;
  }
  const size_t Mc = Mtot / nch;
  const size_t McE = Mc * EDIM;
  const int mblocks = (int)(Mc / 128);
  short* S1b = base;
  short* S2b = S1b + McE;
  short* TV = S2b + McE;  // T1,T2,V1,V2

  convert_wv<<<dim3(256), dim3(256), 0, stream>>>(Wv, Wvb);
  compute_tvec<<<dim3(2), dim3(256), 0, stream>>>(Wk, bq, tvec);
  compute_h<<<dim3(64), dim3(256), 0, stream>>>(Wq, Wk, Hb);

  for (size_t c = 0; c < nch; ++c) {
    const size_t roff = c * Mc;
    convert_x<<<dim3((unsigned)(Mc / 4)), dim3(256), 0, stream>>>(
        state1 + roff * EDIM, state2 + roff * EDIM, tvec, S1b, S2b, w1 + roff, w2 + roff);
    proj_gemm<<<dim3((unsigned)(mblocks * 16)), dim3(256), 0, stream>>>(
        S1b, S2b, Hb, Wvb, bv, TV, McE, mblocks);
    attn_kernel<<<dim3((unsigned)(Mc / 64), 2), dim3(256), 0, stream>>>(
        TV, S1b, S2b, w1 + roff, w2 + roff, out1 + roff * EDIM, out2 + roff * EDIM, McE);
  }
}

// Round 7
// 235.598 us; speedup vs baseline: 1.4105x; 1.1576x over previous
//
#include <hip/hip_runtime.h>
#include <hip/hip_bf16.h>

typedef __attribute__((ext_vector_type(4))) float f32x4;
typedef __attribute__((ext_vector_type(8))) short short8;
typedef __attribute__((ext_vector_type(4))) short short4v;

#define EDIM 512
#define WELEMS 262144  // 512*512

static __device__ __forceinline__ short f2bf(float f) {
  union { float f; unsigned u; } v; v.f = f;
  unsigned r = v.u + 0x7fffu + ((v.u >> 16) & 1u);  // RNE
  return (short)(r >> 16);
}
static __device__ __forceinline__ float bf2f(short s) {
  union { float f; unsigned u; } v; v.u = ((unsigned)(unsigned short)s) << 16;
  return v.f;
}

// async global -> LDS, 16B per lane; lds base wave-uniform + lane*16 linear.
static __device__ __forceinline__ void gload_lds16(const short* g, short* l) {
  __builtin_amdgcn_global_load_lds(
      (const __attribute__((address_space(1))) unsigned int*)g,
      (__attribute__((address_space(3))) unsigned int*)(unsigned int)(unsigned long long)l,
      16, 0, 0);
}

// ---------------- Wv fp32 -> bf16 (tiny) ----------------
__global__ __launch_bounds__(256) void convert_wv(
    const float* __restrict__ Wv, short* __restrict__ Wvb) {
  int i = (blockIdx.x * 256 + threadIdx.x) * 4;
  f32x4 v = *(const f32x4*)(Wv + i);
  short4v vs;
#pragma unroll
  for (int j = 0; j < 4; ++j) vs[j] = f2bf(v[j]);
  *(short4v*)(Wvb + i) = vs;
}

// ------- tvec = Wk^T @ bq. Self-contained: grid(8) x 256; block owns 64 f-cols;
// 4 n-partials per column, fixed-order LDS reduce, direct store (no atomics).
__global__ __launch_bounds__(256) void compute_tvec(
    const float* __restrict__ Wk, const float* __restrict__ bq, float* __restrict__ tvec) {
  __shared__ float red[4][64];
  const int fl = threadIdx.x & 63;
  const int part = threadIdx.x >> 6;
  const int f = blockIdx.x * 64 + fl;
  float s = 0.f;
  const int n0 = part * 128;
#pragma unroll 8
  for (int n = n0; n < n0 + 128; ++n) s += Wk[(size_t)n * EDIM + f] * bq[n];
  red[part][fl] = s;
  __syncthreads();
  if (part == 0)
    tvec[f] = ((red[0][fl] + red[1][fl]) + (red[2][fl] + red[3][fl]));
}

// ------- H[f][e] = sum_n Wk[n,f]*Wq[n,e] (bf16 out) -------
// 256 blocks = 16x16 tiles of 32x32; 2x2 per thread; padded LDS; broadcast reads.
__global__ __launch_bounds__(256) void compute_h(
    const float* __restrict__ Wq, const float* __restrict__ Wk, short* __restrict__ H) {
  __shared__ float Kt[64][33];
  __shared__ float Qt[64][33];
  const int bf = (blockIdx.x >> 4) * 32;
  const int be = (blockIdx.x & 15) * 32;
  const int tid = threadIdx.x;
  const int fh = (tid & 15) * 2;
  const int eh = (tid >> 4) * 2;
  float a00 = 0, a01 = 0, a10 = 0, a11 = 0;
  for (int nc = 0; nc < 8; ++nc) {
    __syncthreads();
#pragma unroll
    for (int p = 0; p < 8; ++p) {
      const int idx = p * 256 + tid;  // 2048 = 64n x 32f
      const int n = idx >> 5, f = idx & 31;
      Kt[n][f] = Wk[(size_t)(nc * 64 + n) * EDIM + bf + f];
      Qt[n][f] = Wq[(size_t)(nc * 64 + n) * EDIM + be + f];
    }
    __syncthreads();
#pragma unroll 4
    for (int n = 0; n < 64; ++n) {
      const float k0 = Kt[n][fh], k1 = Kt[n][fh + 1];
      const float q0 = Qt[n][eh], q1 = Qt[n][eh + 1];
      a00 += k0 * q0; a01 += k0 * q1; a10 += k1 * q0; a11 += k1 * q1;
    }
  }
  H[(size_t)(bf + fh) * EDIM + be + eh] = f2bf(a00);
  H[(size_t)(bf + fh) * EDIM + be + eh + 1] = f2bf(a01);
  H[(size_t)(bf + fh + 1) * EDIM + be + eh] = f2bf(a10);
  H[(size_t)(bf + fh + 1) * EDIM + be + eh + 1] = f2bf(a11);
}

// ------- states fp32 -> bf16 + w = X @ tvec (one wave per row) -------
__global__ __launch_bounds__(256) void convert_x(
    const float* __restrict__ s1, const float* __restrict__ s2,
    const float* __restrict__ tvec,
    short* __restrict__ o1, short* __restrict__ o2,
    float* __restrict__ w1, float* __restrict__ w2) {
  const int wv = threadIdx.x >> 6, lane = threadIdx.x & 63;
  const size_t r = (size_t)blockIdx.x * 4 + wv;
  const int off = lane * 8;
  const f32x4 t0 = *(const f32x4*)(tvec + off);
  const f32x4 t1 = *(const f32x4*)(tvec + off + 4);
#pragma unroll
  for (int st = 0; st < 2; ++st) {
    const float* src = st ? s2 : s1;
    f32x4 a0 = *(const f32x4*)(src + r * EDIM + off);
    f32x4 a1 = *(const f32x4*)(src + r * EDIM + off + 4);
    short8 rb;
    float dot = 0.f;
#pragma unroll
    for (int j = 0; j < 4; ++j) {
      rb[j] = f2bf(a0[j]); dot += a0[j] * t0[j];
      rb[j + 4] = f2bf(a1[j]); dot += a1[j] * t1[j];
    }
    *(short8*)((st ? o2 : o1) + r * EDIM + off) = rb;
#pragma unroll
    for (int d = 1; d < 64; d <<= 1) dot += __shfl_xor(dot, d);
    if (lane == 0) (st ? w2 : w1)[r] = dot;
  }
}

// ------- projection GEMM (r2 structure): out = X @ W^T (+ bv for V slices) -------
// grid = mblocks*16, XCD decode. zn: z=zn>>2 in {T1,T2,V1,V2}, nb=zn&3.
// LDS linear, source pre-swizzled chunk^=(row&7); swizzled ds_read (rule #21).
__global__ __launch_bounds__(256, 3) void proj_gemm(
    const short* __restrict__ S1b, const short* __restrict__ S2b,
    const short* __restrict__ Hb, const short* __restrict__ Wvb,
    const float* __restrict__ bv,
    short* __restrict__ TV, size_t McE, int mblocks) {
  __shared__ short Al[128 * 64];
  __shared__ short Bl[128 * 64];

  int mb, zn;
  {
    const int L = blockIdx.x;
    if ((mblocks & 7) == 0) {
      const int mpx = mblocks >> 3;
      const int xcd = L & 7;
      const int slot = L >> 3;
      mb = xcd * mpx + slot / 16;
      zn = slot % 16;
    } else { mb = L / 16; zn = L % 16; }
  }
  const int z = zn >> 2;   // 0:T1 1:T2 2:V1 3:V2
  const int nb = zn & 3;

  const short* __restrict__ X = (z & 1) ? S2b : S1b;
  const short* __restrict__ W = (z < 2) ? Hb : Wvb;
  short* __restrict__ O = TV + (size_t)z * McE;

  const int m0 = mb * 128;
  const int n0 = nb * 128;
  const int tid = threadIdx.x;
  const int lane = tid & 63;
  const int wv = tid >> 6;
  const int wr = wv >> 1, wc = wv & 1;  // 2x2 waves, 64x64 out each
  const int col = lane & 15;
  const int kg = lane >> 4;

  f32x4 acc[4][4] = {};

  for (int ks = 0; ks < EDIM / 64; ++ks) {
    const int k0 = ks * 64;
    __syncthreads();
#pragma unroll
    for (int j = 0; j < 4; ++j) {
      const int g = (j * 4 + wv) * 64 + lane;
      const int row = g >> 3;
      const int sc = (g & 7) ^ (row & 7);
      gload_lds16(X + (size_t)(m0 + row) * EDIM + k0 + sc * 8, Al + (j * 4 + wv) * 512);
      gload_lds16(W + (size_t)(n0 + row) * EDIM + k0 + sc * 8, Bl + (j * 4 + wv) * 512);
    }
    __syncthreads();
#pragma unroll
    for (int kk = 0; kk < 2; ++kk) {
      short8 af[4], bf8[4];
#pragma unroll
      for (int i = 0; i < 4; ++i) {
        const int ra = wr * 64 + i * 16 + col;
        const int rb = wc * 64 + i * 16 + col;
        af[i]  = *(const short8*)(Al + ra * 64 + ((((kk << 2) + kg) ^ (ra & 7)) << 3));
        bf8[i] = *(const short8*)(Bl + rb * 64 + ((((kk << 2) + kg) ^ (rb & 7)) << 3));
      }
#pragma unroll
      for (int mi = 0; mi < 4; ++mi)
#pragma unroll
        for (int nj = 0; nj < 4; ++nj)
          acc[mi][nj] = __builtin_amdgcn_mfma_f32_16x16x32_bf16(af[mi], bf8[nj], acc[mi][nj], 0, 0, 0);
    }
  }

  // epilogue: row-major store order (consecutive nj -> contiguous 128B per row)
#pragma unroll
  for (int mi = 0; mi < 4; ++mi) {
#pragma unroll
    for (int j = 0; j < 4; ++j) {
      const size_t r = m0 + wr * 64 + mi * 16 + kg * 4 + j;
#pragma unroll
      for (int nj = 0; nj < 4; ++nj) {
        const int e = n0 + wc * 64 + nj * 16 + col;
        const float bb = (z < 2) ? 0.f : bv[e];
        O[r * EDIM + e] = f2bf(acc[mi][nj][j] + bb);
      }
    }
  }
}

// ------- block attention: S = T@X^T + w[j]; softmax; @V. one wave per 16-row block --
__global__ __launch_bounds__(256) void attn_kernel(
    const short* __restrict__ TV, const short* __restrict__ S1b, const short* __restrict__ S2b,
    const float* __restrict__ w1, const float* __restrict__ w2,
    float* __restrict__ out1, float* __restrict__ out2, size_t McE) {
  __shared__ float plds[4][16][16];
  const int dir = blockIdx.y;
  const short* __restrict__ Q = TV + (dir ? McE : 0);          // T2 : T1
  const short* __restrict__ K = dir ? S1b : S2b;
  const short* __restrict__ V = TV + (dir ? 2 : 3) * McE;      // V1 : V2
  const float* __restrict__ w = dir ? w1 : w2;
  float* __restrict__ O = dir ? out2 : out1;

  const int lane = threadIdx.x & 63;
  const int wv = threadIdx.x >> 6;
  const size_t r0 = ((size_t)blockIdx.x * 4 + wv) * 16;
  const int col = lane & 15;
  const int kg = lane >> 4;

  const short* Qp = Q + (r0 + col) * EDIM + kg * 8;
  const short* Kp = K + (r0 + col) * EDIM + kg * 8;
  f32x4 s = {};
#pragma unroll
  for (int ks = 0; ks < 16; ++ks) {
    short8 a = *(const short8*)(Qp + ks * 32);
    short8 b = *(const short8*)(Kp + ks * 32);
    s = __builtin_amdgcn_mfma_f32_16x16x32_bf16(a, b, s, 0, 0, 0);
  }
  const float scale = 0.04419417382415922f;  // 1/sqrt(512)
  const float wj = w[r0 + col];              // per-k-column bias term
  float p[4];
#pragma unroll
  for (int j = 0; j < 4; ++j) p[j] = (s[j] + wj) * scale;
#pragma unroll
  for (int j = 0; j < 4; ++j) {
    float m = p[j];
#pragma unroll
    for (int d = 1; d < 16; d <<= 1) m = fmaxf(m, __shfl_xor(m, d));
    float e = __expf(p[j] - m);
    float ssum = e;
#pragma unroll
    for (int d = 1; d < 16; d <<= 1) ssum += __shfl_xor(ssum, d);
    p[j] = e / ssum;
  }
#pragma unroll
  for (int j = 0; j < 4; ++j) plds[wv][kg * 4 + j][col] = p[j];
  __syncthreads();

  const int e0 = lane * 8;
  short8 v8[16];
#pragma unroll
  for (int k = 0; k < 16; ++k) v8[k] = *(const short8*)(V + (r0 + k) * EDIM + e0);
#pragma unroll
  for (int q = 0; q < 16; ++q) {
    float acc[8] = {0, 0, 0, 0, 0, 0, 0, 0};
#pragma unroll
    for (int k = 0; k < 16; ++k) {
      const float pv = plds[wv][q][k];
#pragma unroll
      for (int i = 0; i < 8; ++i) acc[i] += pv * bf2f(v8[k][i]);
    }
    f32x4 o0 = {acc[0], acc[1], acc[2], acc[3]};
    f32x4 o1 = {acc[4], acc[5], acc[6], acc[7]};
    *(f32x4*)(O + (r0 + q) * EDIM + e0) = o0;
    *(f32x4*)(O + (r0 + q) * EDIM + e0 + 4) = o1;
  }
}

// ---------------- host ----------------
extern "C" void kernel_launch(void* const* d_in, const int* in_sizes, int n_in,
                              void* d_out, int out_size, void* d_ws, size_t ws_size,
                              hipStream_t stream) {
  const float* state1 = (const float*)d_in[0];
  const float* state2 = (const float*)d_in[1];
  const float* Wq = (const float*)d_in[2];
  const float* bq = (const float*)d_in[3];
  const float* Wk = (const float*)d_in[4];
  // d_in[5] = bk: only enters via softmax-invariant terms -> unused
  const float* Wv = (const float*)d_in[6];
  const float* bv = (const float*)d_in[7];

  const size_t Mtot = (size_t)8 * 4096;
  float* out1 = (float*)d_out;
  float* out2 = out1 + Mtot * EDIM;

  // ws layout: Wvb | Hb | tvec | w1 | w2 | per-chunk {S1b, S2b, TV[4]}
  short* Wvb = (short*)d_ws;
  short* Hb = Wvb + WELEMS;
  float* tvec = (float*)(Hb + WELEMS);
  float* w1 = tvec + EDIM;
  float* w2 = w1 + Mtot;
  short* base = (short*)(w2 + Mtot);

  const size_t fixed_bytes = (size_t)(2 * WELEMS) * 2 + (EDIM + 2 * Mtot) * 4;
  size_t nch = 1;
  while (nch < 256) {
    size_t need = fixed_bytes + (size_t)6 * (Mtot / nch) * EDIM * 2;
    if (need <= ws_size) break;
    nch <<= 1;
  }
  const size_t Mc = Mtot / nch;
  const size_t McE = Mc * EDIM;
  const int mblocks = (int)(Mc / 128);
  short* S1b = base;
  short* S2b = S1b + McE;
  short* TV = S2b + McE;  // T1,T2,V1,V2

  convert_wv<<<dim3(256), dim3(256), 0, stream>>>(Wv, Wvb);
  compute_tvec<<<dim3(8), dim3(256), 0, stream>>>(Wk, bq, tvec);
  compute_h<<<dim3(256), dim3(256), 0, stream>>>(Wq, Wk, Hb);

  for (size_t c = 0; c < nch; ++c) {
    const size_t roff = c * Mc;
    convert_x<<<dim3((unsigned)(Mc / 4)), dim3(256), 0, stream>>>(
        state1 + roff * EDIM, state2 + roff * EDIM, tvec, S1b, S2b, w1 + roff, w2 + roff);
    proj_gemm<<<dim3((unsigned)(mblocks * 16)), dim3(256), 0, stream>>>(
        S1b, S2b, Hb, Wvb, bv, TV, McE, mblocks);
    attn_kernel<<<dim3((unsigned)(Mc / 64), 2), dim3(256), 0, stream>>>(
        TV, S1b, S2b, w1 + roff, w2 + roff, out1 + roff * EDIM, out2 + roff * EDIM, McE);
  }
}

// Round 8
// 231.725 us; speedup vs baseline: 1.4341x; 1.0167x over previous
//
#include <hip/hip_runtime.h>
#include <hip/hip_bf16.h>

typedef __attribute__((ext_vector_type(4))) float f32x4;
typedef __attribute__((ext_vector_type(8))) short short8;
typedef __attribute__((ext_vector_type(4))) short short4v;

#define EDIM 512
#define WELEMS 262144  // 512*512

static __device__ __forceinline__ short f2bf(float f) {
  union { float f; unsigned u; } v; v.f = f;
  unsigned r = v.u + 0x7fffu + ((v.u >> 16) & 1u);  // RNE
  return (short)(r >> 16);
}
static __device__ __forceinline__ float bf2f(short s) {
  union { float f; unsigned u; } v; v.u = ((unsigned)(unsigned short)s) << 16;
  return v.f;
}

// async global -> LDS, 16B per lane; lds base wave-uniform + lane*16 linear.
static __device__ __forceinline__ void gload_lds16(const short* g, short* l) {
  __builtin_amdgcn_global_load_lds(
      (const __attribute__((address_space(1))) unsigned int*)g,
      (__attribute__((address_space(3))) unsigned int*)(unsigned int)(unsigned long long)l,
      16, 0, 0);
}

// ---- merged prep: [0,256) convert Wv->bf16 | [256,264) tvec | [264,520) H ----
// tvec = Wk^T @ bq (fixed-order LDS reduce, no atomics).
// H[f][e] = sum_n Wk[n,f]*Wq[n,e], bf16 out.
__global__ __launch_bounds__(256) void prep(
    const float* __restrict__ Wq, const float* __restrict__ bq,
    const float* __restrict__ Wk, const float* __restrict__ Wv,
    short* __restrict__ Wvb, float* __restrict__ tvec, short* __restrict__ Hb) {
  __shared__ float sh[2][64][33];
  const int b = blockIdx.x;
  const int tid = threadIdx.x;
  if (b < 256) {
    int i = (b * 256 + tid) * 4;
    f32x4 v = *(const f32x4*)(Wv + i);
    short4v vs;
#pragma unroll
    for (int j = 0; j < 4; ++j) vs[j] = f2bf(v[j]);
    *(short4v*)(Wvb + i) = vs;
  } else if (b < 264) {
    float* red = &sh[0][0][0];  // [4][64]
    const int fl = tid & 63;
    const int part = tid >> 6;
    const int f = (b - 256) * 64 + fl;
    float s = 0.f;
    const int n0 = part * 128;
#pragma unroll 8
    for (int n = n0; n < n0 + 128; ++n) s += Wk[(size_t)n * EDIM + f] * bq[n];
    red[part * 64 + fl] = s;
    __syncthreads();
    if (part == 0)
      tvec[f] = ((red[fl] + red[64 + fl]) + (red[128 + fl] + red[192 + fl]));
  } else {
    const int hb = b - 264;
    const int bf = (hb >> 4) * 32;
    const int be = (hb & 15) * 32;
    const int fh = (tid & 15) * 2;
    const int eh = (tid >> 4) * 2;
    float a00 = 0, a01 = 0, a10 = 0, a11 = 0;
    for (int nc = 0; nc < 8; ++nc) {
      __syncthreads();
#pragma unroll
      for (int p = 0; p < 8; ++p) {
        const int idx = p * 256 + tid;  // 2048 = 64n x 32f
        const int n = idx >> 5, f = idx & 31;
        sh[0][n][f] = Wk[(size_t)(nc * 64 + n) * EDIM + bf + f];
        sh[1][n][f] = Wq[(size_t)(nc * 64 + n) * EDIM + be + f];
      }
      __syncthreads();
#pragma unroll 4
      for (int n = 0; n < 64; ++n) {
        const float k0 = sh[0][n][fh], k1 = sh[0][n][fh + 1];
        const float q0 = sh[1][n][eh], q1 = sh[1][n][eh + 1];
        a00 += k0 * q0; a01 += k0 * q1; a10 += k1 * q0; a11 += k1 * q1;
      }
    }
    Hb[(size_t)(bf + fh) * EDIM + be + eh] = f2bf(a00);
    Hb[(size_t)(bf + fh) * EDIM + be + eh + 1] = f2bf(a01);
    Hb[(size_t)(bf + fh + 1) * EDIM + be + eh] = f2bf(a10);
    Hb[(size_t)(bf + fh + 1) * EDIM + be + eh + 1] = f2bf(a11);
  }
}

// ------- states fp32 -> bf16 + w = X @ tvec (one wave per row) -------
__global__ __launch_bounds__(256) void convert_x(
    const float* __restrict__ s1, const float* __restrict__ s2,
    const float* __restrict__ tvec,
    short* __restrict__ o1, short* __restrict__ o2,
    float* __restrict__ w1, float* __restrict__ w2) {
  const int wv = threadIdx.x >> 6, lane = threadIdx.x & 63;
  const size_t r = (size_t)blockIdx.x * 4 + wv;
  const int off = lane * 8;
  const f32x4 t0 = *(const f32x4*)(tvec + off);
  const f32x4 t1 = *(const f32x4*)(tvec + off + 4);
#pragma unroll
  for (int st = 0; st < 2; ++st) {
    const float* src = st ? s2 : s1;
    f32x4 a0 = *(const f32x4*)(src + r * EDIM + off);
    f32x4 a1 = *(const f32x4*)(src + r * EDIM + off + 4);
    short8 rb;
    float dot = 0.f;
#pragma unroll
    for (int j = 0; j < 4; ++j) {
      rb[j] = f2bf(a0[j]); dot += a0[j] * t0[j];
      rb[j + 4] = f2bf(a1[j]); dot += a1[j] * t1[j];
    }
    *(short8*)((st ? o2 : o1) + r * EDIM + off) = rb;
#pragma unroll
    for (int d = 1; d < 64; d <<= 1) dot += __shfl_xor(dot, d);
    if (lane == 0) (st ? w2 : w1)[r] = dot;
  }
}

// ------- projection GEMM: out = X @ W^T (+ bv for V slices) -------
// BK=32 double-buffered 2-phase: issue next-tile gload_lds before computing the
// current buffer; one barrier per iter (its implicit vmcnt(0) drain lands after
// the MFMA phase -> load latency hidden within the block).
// grid = mblocks*16, XCD decode. zn: z=zn>>2 in {T1,T2,V1,V2}, nb=zn&3.
// Swizzle (rule #21, both sides): source chunk c^=(row&3); ds_read chunk kg^(row&3).
__global__ __launch_bounds__(256, 4) void proj_gemm(
    const short* __restrict__ S1b, const short* __restrict__ S2b,
    const short* __restrict__ Hb, const short* __restrict__ Wvb,
    const float* __restrict__ bv,
    short* __restrict__ TV, size_t McE, int mblocks) {
  __shared__ short lds[2][2][4096];  // [buf][A/B][128 rows x 32 bf16]

  int mb, zn;
  {
    const int L = blockIdx.x;
    if ((mblocks & 7) == 0) {
      const int mpx = mblocks >> 3;
      const int xcd = L & 7;
      const int slot = L >> 3;
      mb = xcd * mpx + slot / 16;
      zn = slot % 16;
    } else { mb = L / 16; zn = L % 16; }
  }
  const int z = zn >> 2;   // 0:T1 1:T2 2:V1 3:V2
  const int nb = zn & 3;

  const short* __restrict__ X = (z & 1) ? S2b : S1b;
  const short* __restrict__ W = (z < 2) ? Hb : Wvb;
  short* __restrict__ O = TV + (size_t)z * McE;

  const int m0 = mb * 128;
  const int n0 = nb * 128;
  const int tid = threadIdx.x;
  const int lane = tid & 63;
  const int wv = tid >> 6;
  const int wr = wv >> 1, wc = wv & 1;  // 2x2 waves, 64x64 out each
  const int col = lane & 15;
  const int kg = lane >> 4;

  auto STAGE = [&](int ks, int buf) {
    const int k0 = ks * 32;
#pragma unroll
    for (int j = 0; j < 2; ++j) {
      const int g = (j * 4 + wv) * 64 + lane;  // 16B-chunk id, 0..511
      const int row = g >> 2;                  // 4 chunks per 64B row
      const int sc = (g & 3) ^ (row & 3);      // inverse swizzle on SOURCE
      gload_lds16(X + (size_t)(m0 + row) * EDIM + k0 + sc * 8,
                  &lds[buf][0][(j * 4 + wv) * 512]);
      gload_lds16(W + (size_t)(n0 + row) * EDIM + k0 + sc * 8,
                  &lds[buf][1][(j * 4 + wv) * 512]);
    }
  };

  f32x4 acc[4][4] = {};

  STAGE(0, 0);
  __syncthreads();  // drains vmcnt(0): buf0 ready
  int cur = 0;
#pragma unroll
  for (int ks = 0; ks < 16; ++ks) {
    if (ks < 15) STAGE(ks + 1, cur ^ 1);  // prefetch flies under compute
    const short* Ar = &lds[cur][0][0];
    const short* Br = &lds[cur][1][0];
    short8 af[4], bf8[4];
#pragma unroll
    for (int i = 0; i < 4; ++i) {
      const int ra = wr * 64 + i * 16 + col;
      const int rb = wc * 64 + i * 16 + col;
      af[i]  = *(const short8*)(Ar + ra * 32 + ((kg ^ (ra & 3)) << 3));
      bf8[i] = *(const short8*)(Br + rb * 32 + ((kg ^ (rb & 3)) << 3));
    }
#pragma unroll
    for (int mi = 0; mi < 4; ++mi)
#pragma unroll
      for (int nj = 0; nj < 4; ++nj)
        acc[mi][nj] = __builtin_amdgcn_mfma_f32_16x16x32_bf16(af[mi], bf8[nj], acc[mi][nj], 0, 0, 0);
    if (ks < 15) __syncthreads();  // implicit vmcnt(0)+lgkm drain: next buf ready
    cur ^= 1;
  }

  // epilogue: C frag row=(lane>>4)*4+j, col=lane&15; add bias; store bf16
  // (64 scalar 2B stores/thread ~ 1.7 us chip-wide total; L2 write-combines)
#pragma unroll
  for (int mi = 0; mi < 4; ++mi) {
#pragma unroll
    for (int j = 0; j < 4; ++j) {
      const size_t r = m0 + wr * 64 + mi * 16 + kg * 4 + j;
#pragma unroll
      for (int nj = 0; nj < 4; ++nj) {
        const int e = n0 + wc * 64 + nj * 16 + col;
        const float bb = (z < 2) ? 0.f : bv[e];
        O[r * EDIM + e] = f2bf(acc[mi][nj][j] + bb);
      }
    }
  }
}

// ------- block attention: S = T@X^T + w[j]; softmax; @V. one wave per 16-row block --
__global__ __launch_bounds__(256) void attn_kernel(
    const short* __restrict__ TV, const short* __restrict__ S1b, const short* __restrict__ S2b,
    const float* __restrict__ w1, const float* __restrict__ w2,
    float* __restrict__ out1, float* __restrict__ out2, size_t McE) {
  __shared__ float plds[4][16][16];
  const int dir = blockIdx.y;
  const short* __restrict__ Q = TV + (dir ? McE : 0);          // T2 : T1
  const short* __restrict__ K = dir ? S1b : S2b;
  const short* __restrict__ V = TV + (dir ? 2 : 3) * McE;      // V1 : V2
  const float* __restrict__ w = dir ? w1 : w2;
  float* __restrict__ O = dir ? out2 : out1;

  const int lane = threadIdx.x & 63;
  const int wv = threadIdx.x >> 6;
  const size_t r0 = ((size_t)blockIdx.x * 4 + wv) * 16;
  const int col = lane & 15;
  const int kg = lane >> 4;

  const short* Qp = Q + (r0 + col) * EDIM + kg * 8;
  const short* Kp = K + (r0 + col) * EDIM + kg * 8;
  f32x4 s = {};
#pragma unroll
  for (int ks = 0; ks < 16; ++ks) {
    short8 a = *(const short8*)(Qp + ks * 32);
    short8 b = *(const short8*)(Kp + ks * 32);
    s = __builtin_amdgcn_mfma_f32_16x16x32_bf16(a, b, s, 0, 0, 0);
  }
  const float scale = 0.04419417382415922f;  // 1/sqrt(512)
  const float wj = w[r0 + col];              // per-k-column bias term
  float p[4];
#pragma unroll
  for (int j = 0; j < 4; ++j) p[j] = (s[j] + wj) * scale;
#pragma unroll
  for (int j = 0; j < 4; ++j) {
    float m = p[j];
#pragma unroll
    for (int d = 1; d < 16; d <<= 1) m = fmaxf(m, __shfl_xor(m, d));
    float e = __expf(p[j] - m);
    float ssum = e;
#pragma unroll
    for (int d = 1; d < 16; d <<= 1) ssum += __shfl_xor(ssum, d);
    p[j] = e / ssum;
  }
#pragma unroll
  for (int j = 0; j < 4; ++j) plds[wv][kg * 4 + j][col] = p[j];
  __syncthreads();

  const int e0 = lane * 8;
  short8 v8[16];
#pragma unroll
  for (int k = 0; k < 16; ++k) v8[k] = *(const short8*)(V + (r0 + k) * EDIM + e0);
#pragma unroll
  for (int q = 0; q < 16; ++q) {
    float acc[8] = {0, 0, 0, 0, 0, 0, 0, 0};
#pragma unroll
    for (int k = 0; k < 16; ++k) {
      const float pv = plds[wv][q][k];
#pragma unroll
      for (int i = 0; i < 8; ++i) acc[i] += pv * bf2f(v8[k][i]);
    }
    f32x4 o0 = {acc[0], acc[1], acc[2], acc[3]};
    f32x4 o1 = {acc[4], acc[5], acc[6], acc[7]};
    *(f32x4*)(O + (r0 + q) * EDIM + e0) = o0;
    *(f32x4*)(O + (r0 + q) * EDIM + e0 + 4) = o1;
  }
}

// ---------------- host ----------------
extern "C" void kernel_launch(void* const* d_in, const int* in_sizes, int n_in,
                              void* d_out, int out_size, void* d_ws, size_t ws_size,
                              hipStream_t stream) {
  const float* state1 = (const float*)d_in[0];
  const float* state2 = (const float*)d_in[1];
  const float* Wq = (const float*)d_in[2];
  const float* bq = (const float*)d_in[3];
  const float* Wk = (const float*)d_in[4];
  // d_in[5] = bk: only enters via softmax-invariant terms -> unused
  const float* Wv = (const float*)d_in[6];
  const float* bv = (const float*)d_in[7];

  const size_t Mtot = (size_t)8 * 4096;
  float* out1 = (float*)d_out;
  float* out2 = out1 + Mtot * EDIM;

  // ws layout: Wvb | Hb | tvec | w1 | w2 | per-chunk {S1b, S2b, TV[4]}
  short* Wvb = (short*)d_ws;
  short* Hb = Wvb + WELEMS;
  float* tvec = (float*)(Hb + WELEMS);
  float* w1 = tvec + EDIM;
  float* w2 = w1 + Mtot;
  short* base = (short*)(w2 + Mtot);

  const size_t fixed_bytes = (size_t)(2 * WELEMS) * 2 + (EDIM + 2 * Mtot) * 4;
  size_t nch = 1;
  while (nch < 256) {
    size_t need = fixed_bytes + (size_t)6 * (Mtot / nch) * EDIM * 2;
    if (need <= ws_size) break;
    nch <<= 1;
  }
  const size_t Mc = Mtot / nch;
  const size_t McE = Mc * EDIM;
  const int mblocks = (int)(Mc / 128);
  short* S1b = base;
  short* S2b = S1b + McE;
  short* TV = S2b + McE;  // T1,T2,V1,V2

  prep<<<dim3(520), dim3(256), 0, stream>>>(Wq, bq, Wk, Wv, Wvb, tvec, Hb);

  for (size_t c = 0; c < nch; ++c) {
    const size_t roff = c * Mc;
    convert_x<<<dim3((unsigned)(Mc / 4)), dim3(256), 0, stream>>>(
        state1 + roff * EDIM, state2 + roff * EDIM, tvec, S1b, S2b, w1 + roff, w2 + roff);
    proj_gemm<<<dim3((unsigned)(mblocks * 16)), dim3(256), 0, stream>>>(
        S1b, S2b, Hb, Wvb, bv, TV, McE, mblocks);
    attn_kernel<<<dim3((unsigned)(Mc / 64), 2), dim3(256), 0, stream>>>(
        TV, S1b, S2b, w1 + roff, w2 + roff, out1 + roff * EDIM, out2 + roff * EDIM, McE);
  }
}

// Round 9
// 200.120 us; speedup vs baseline: 1.6605x; 1.1579x over previous
//
#include <hip/hip_runtime.h>
#include <hip/hip_bf16.h>

typedef __attribute__((ext_vector_type(4))) float f32x4;
typedef __attribute__((ext_vector_type(8))) short short8;
typedef __attribute__((ext_vector_type(4))) short short4v;

#define EDIM 512
#define WELEMS 262144  // 512*512

static __device__ __forceinline__ short f2bf(float f) {
  union { float f; unsigned u; } v; v.f = f;
  unsigned r = v.u + 0x7fffu + ((v.u >> 16) & 1u);  // RNE
  return (short)(r >> 16);
}
static __device__ __forceinline__ float bf2f(short s) {
  union { float f; unsigned u; } v; v.u = ((unsigned)(unsigned short)s) << 16;
  return v.f;
}

// async global -> LDS, 16B per lane; lds base wave-uniform + lane*16 linear.
static __device__ __forceinline__ void gload_lds16(const short* g, short* l) {
  __builtin_amdgcn_global_load_lds(
      (const __attribute__((address_space(1))) unsigned int*)g,
      (__attribute__((address_space(3))) unsigned int*)(unsigned int)(unsigned long long)l,
      16, 0, 0);
}

// ---- merged prep: [0,256) convert Wv->bf16 | [256,264) tvec | [264,520) H ----
__global__ __launch_bounds__(256) void prep(
    const float* __restrict__ Wq, const float* __restrict__ bq,
    const float* __restrict__ Wk, const float* __restrict__ Wv,
    short* __restrict__ Wvb, float* __restrict__ tvec, short* __restrict__ Hb) {
  __shared__ float sh[2][64][33];
  const int b = blockIdx.x;
  const int tid = threadIdx.x;
  if (b < 256) {
    int i = (b * 256 + tid) * 4;
    f32x4 v = *(const f32x4*)(Wv + i);
    short4v vs;
#pragma unroll
    for (int j = 0; j < 4; ++j) vs[j] = f2bf(v[j]);
    *(short4v*)(Wvb + i) = vs;
  } else if (b < 264) {
    float* red = &sh[0][0][0];  // [4][64]
    const int fl = tid & 63;
    const int part = tid >> 6;
    const int f = (b - 256) * 64 + fl;
    float s = 0.f;
    const int n0 = part * 128;
#pragma unroll 8
    for (int n = n0; n < n0 + 128; ++n) s += Wk[(size_t)n * EDIM + f] * bq[n];
    red[part * 64 + fl] = s;
    __syncthreads();
    if (part == 0)
      tvec[f] = ((red[fl] + red[64 + fl]) + (red[128 + fl] + red[192 + fl]));
  } else {
    const int hb = b - 264;
    const int bf = (hb >> 4) * 32;
    const int be = (hb & 15) * 32;
    const int fh = (tid & 15) * 2;
    const int eh = (tid >> 4) * 2;
    float a00 = 0, a01 = 0, a10 = 0, a11 = 0;
    for (int nc = 0; nc < 8; ++nc) {
      __syncthreads();
#pragma unroll
      for (int p = 0; p < 8; ++p) {
        const int idx = p * 256 + tid;  // 2048 = 64n x 32f
        const int n = idx >> 5, f = idx & 31;
        sh[0][n][f] = Wk[(size_t)(nc * 64 + n) * EDIM + bf + f];
        sh[1][n][f] = Wq[(size_t)(nc * 64 + n) * EDIM + be + f];
      }
      __syncthreads();
#pragma unroll 4
      for (int n = 0; n < 64; ++n) {
        const float k0 = sh[0][n][fh], k1 = sh[0][n][fh + 1];
        const float q0 = sh[1][n][eh], q1 = sh[1][n][eh + 1];
        a00 += k0 * q0; a01 += k0 * q1; a10 += k1 * q0; a11 += k1 * q1;
      }
    }
    Hb[(size_t)(bf + fh) * EDIM + be + eh] = f2bf(a00);
    Hb[(size_t)(bf + fh) * EDIM + be + eh + 1] = f2bf(a01);
    Hb[(size_t)(bf + fh + 1) * EDIM + be + eh] = f2bf(a10);
    Hb[(size_t)(bf + fh + 1) * EDIM + be + eh + 1] = f2bf(a11);
  }
}

// ------- states fp32 -> bf16 + w = X @ tvec (one wave per row) -------
__global__ __launch_bounds__(256) void convert_x(
    const float* __restrict__ s1, const float* __restrict__ s2,
    const float* __restrict__ tvec,
    short* __restrict__ o1, short* __restrict__ o2,
    float* __restrict__ w1, float* __restrict__ w2) {
  const int wv = threadIdx.x >> 6, lane = threadIdx.x & 63;
  const size_t r = (size_t)blockIdx.x * 4 + wv;
  const int off = lane * 8;
  const f32x4 t0 = *(const f32x4*)(tvec + off);
  const f32x4 t1 = *(const f32x4*)(tvec + off + 4);
#pragma unroll
  for (int st = 0; st < 2; ++st) {
    const float* src = st ? s2 : s1;
    f32x4 a0 = *(const f32x4*)(src + r * EDIM + off);
    f32x4 a1 = *(const f32x4*)(src + r * EDIM + off + 4);
    short8 rb;
    float dot = 0.f;
#pragma unroll
    for (int j = 0; j < 4; ++j) {
      rb[j] = f2bf(a0[j]); dot += a0[j] * t0[j];
      rb[j + 4] = f2bf(a1[j]); dot += a1[j] * t1[j];
    }
    *(short8*)((st ? o2 : o1) + r * EDIM + off) = rb;
#pragma unroll
    for (int d = 1; d < 64; d <<= 1) dot += __shfl_xor(dot, d);
    if (lane == 0) (st ? w2 : w1)[r] = dot;
  }
}

// ------- T GEMM (r7 structure): T_d = X_d @ H^T, bf16 out -------
// grid = mblocks*8: zn = 8 combos (2 dirs x 4 nb), XCD decode.
__global__ __launch_bounds__(256, 3) void proj_t(
    const short* __restrict__ S1b, const short* __restrict__ S2b,
    const short* __restrict__ Hb,
    short* __restrict__ TV, size_t McE, int mblocks) {
  __shared__ short Al[128 * 64];
  __shared__ short Bl[128 * 64];

  int mb, zn;
  {
    const int L = blockIdx.x;
    if ((mblocks & 7) == 0) {
      const int mpx = mblocks >> 3;
      const int xcd = L & 7;
      const int slot = L >> 3;
      mb = xcd * mpx + slot / 8;
      zn = slot % 8;
    } else { mb = L / 8; zn = L % 8; }
  }
  const int z = zn >> 2;   // dir
  const int nb = zn & 3;

  const short* __restrict__ X = z ? S2b : S1b;
  short* __restrict__ O = TV + (size_t)z * McE;

  const int m0 = mb * 128;
  const int n0 = nb * 128;
  const int tid = threadIdx.x;
  const int lane = tid & 63;
  const int wv = tid >> 6;
  const int wr = wv >> 1, wc = wv & 1;
  const int col = lane & 15;
  const int kg = lane >> 4;

  f32x4 acc[4][4] = {};

  for (int ks = 0; ks < EDIM / 64; ++ks) {
    const int k0 = ks * 64;
    __syncthreads();
#pragma unroll
    for (int j = 0; j < 4; ++j) {
      const int g = (j * 4 + wv) * 64 + lane;
      const int row = g >> 3;
      const int sc = (g & 7) ^ (row & 7);
      gload_lds16(X + (size_t)(m0 + row) * EDIM + k0 + sc * 8, Al + (j * 4 + wv) * 512);
      gload_lds16(Hb + (size_t)(n0 + row) * EDIM + k0 + sc * 8, Bl + (j * 4 + wv) * 512);
    }
    __syncthreads();
#pragma unroll
    for (int kk = 0; kk < 2; ++kk) {
      short8 af[4], bf8[4];
#pragma unroll
      for (int i = 0; i < 4; ++i) {
        const int ra = wr * 64 + i * 16 + col;
        const int rb = wc * 64 + i * 16 + col;
        af[i]  = *(const short8*)(Al + ra * 64 + ((((kk << 2) + kg) ^ (ra & 7)) << 3));
        bf8[i] = *(const short8*)(Bl + rb * 64 + ((((kk << 2) + kg) ^ (rb & 7)) << 3));
      }
#pragma unroll
      for (int mi = 0; mi < 4; ++mi)
#pragma unroll
        for (int nj = 0; nj < 4; ++nj)
          acc[mi][nj] = __builtin_amdgcn_mfma_f32_16x16x32_bf16(af[mi], bf8[nj], acc[mi][nj], 0, 0, 0);
    }
  }

#pragma unroll
  for (int mi = 0; mi < 4; ++mi) {
#pragma unroll
    for (int j = 0; j < 4; ++j) {
      const size_t r = m0 + wr * 64 + mi * 16 + kg * 4 + j;
#pragma unroll
      for (int nj = 0; nj < 4; ++nj) {
        const int e = n0 + wc * 64 + nj * 16 + col;
        O[r * EDIM + e] = f2bf(acc[mi][nj][j]);
      }
    }
  }
}

// ------- block attention -> Y = P @ X (bf16): S = T@X^T + w[j]; softmax; P@X ----
// V is algebraically eliminated: out = (P@X)@Wv^T + bv (P row-stochastic).
__global__ __launch_bounds__(256) void attn_y(
    const short* __restrict__ TV, const short* __restrict__ S1b, const short* __restrict__ S2b,
    const float* __restrict__ w1, const float* __restrict__ w2, size_t McE) {
  __shared__ float plds[4][16][16];
  const int dir = blockIdx.y;
  const short* __restrict__ Q = TV + (size_t)dir * McE;     // T1 : T2
  const short* __restrict__ KV = dir ? S1b : S2b;           // K and "V" are the same X
  const float* __restrict__ w = dir ? w1 : w2;
  short* __restrict__ Y = (short*)TV + (size_t)(2 + dir) * McE;

  const int lane = threadIdx.x & 63;
  const int wv = threadIdx.x >> 6;
  const size_t r0 = ((size_t)blockIdx.x * 4 + wv) * 16;
  const int col = lane & 15;
  const int kg = lane >> 4;

  const short* Qp = Q + (r0 + col) * EDIM + kg * 8;
  const short* Kp = KV + (r0 + col) * EDIM + kg * 8;
  f32x4 s = {};
#pragma unroll
  for (int ks = 0; ks < 16; ++ks) {
    short8 a = *(const short8*)(Qp + ks * 32);
    short8 b = *(const short8*)(Kp + ks * 32);
    s = __builtin_amdgcn_mfma_f32_16x16x32_bf16(a, b, s, 0, 0, 0);
  }
  const float scale = 0.04419417382415922f;  // 1/sqrt(512)
  const float wj = w[r0 + col];
  float p[4];
#pragma unroll
  for (int j = 0; j < 4; ++j) p[j] = (s[j] + wj) * scale;
#pragma unroll
  for (int j = 0; j < 4; ++j) {
    float m = p[j];
#pragma unroll
    for (int d = 1; d < 16; d <<= 1) m = fmaxf(m, __shfl_xor(m, d));
    float e = __expf(p[j] - m);
    float ssum = e;
#pragma unroll
    for (int d = 1; d < 16; d <<= 1) ssum += __shfl_xor(ssum, d);
    p[j] = e / ssum;
  }
#pragma unroll
  for (int j = 0; j < 4; ++j) plds[wv][kg * 4 + j][col] = p[j];
  __syncthreads();

  const int e0 = lane * 8;
  short8 v8[16];
#pragma unroll
  for (int k = 0; k < 16; ++k) v8[k] = *(const short8*)(KV + (r0 + k) * EDIM + e0);
#pragma unroll
  for (int q = 0; q < 16; ++q) {
    float acc[8] = {0, 0, 0, 0, 0, 0, 0, 0};
#pragma unroll
    for (int k = 0; k < 16; ++k) {
      const float pv = plds[wv][q][k];
#pragma unroll
      for (int i = 0; i < 8; ++i) acc[i] += pv * bf2f(v8[k][i]);
    }
    short8 y;
#pragma unroll
    for (int i = 0; i < 8; ++i) y[i] = f2bf(acc[i]);
    *(short8*)(Y + (r0 + q) * EDIM + e0) = y;
  }
}

// ------- out GEMM (r7 structure): out_d = Y_d @ Wv^T + bv, fp32 out -------
// grid = mblocks*8: zn = 8 combos (2 dirs x 4 nb), XCD decode.
__global__ __launch_bounds__(256, 3) void out_gemm(
    const short* __restrict__ TV, const short* __restrict__ Wvb,
    const float* __restrict__ bv,
    float* __restrict__ out1, float* __restrict__ out2, size_t McE, int mblocks) {
  __shared__ short Al[128 * 64];
  __shared__ short Bl[128 * 64];

  int mb, zn;
  {
    const int L = blockIdx.x;
    if ((mblocks & 7) == 0) {
      const int mpx = mblocks >> 3;
      const int xcd = L & 7;
      const int slot = L >> 3;
      mb = xcd * mpx + slot / 8;
      zn = slot % 8;
    } else { mb = L / 8; zn = L % 8; }
  }
  const int z = zn >> 2;   // dir
  const int nb = zn & 3;

  const short* __restrict__ A = TV + (size_t)(2 + z) * McE;  // Y1 : Y2
  float* __restrict__ O = z ? out2 : out1;

  const int m0 = mb * 128;
  const int n0 = nb * 128;
  const int tid = threadIdx.x;
  const int lane = tid & 63;
  const int wv = tid >> 6;
  const int wr = wv >> 1, wc = wv & 1;
  const int col = lane & 15;
  const int kg = lane >> 4;

  f32x4 acc[4][4] = {};

  for (int ks = 0; ks < EDIM / 64; ++ks) {
    const int k0 = ks * 64;
    __syncthreads();
#pragma unroll
    for (int j = 0; j < 4; ++j) {
      const int g = (j * 4 + wv) * 64 + lane;
      const int row = g >> 3;
      const int sc = (g & 7) ^ (row & 7);
      gload_lds16(A + (size_t)(m0 + row) * EDIM + k0 + sc * 8, Al + (j * 4 + wv) * 512);
      gload_lds16(Wvb + (size_t)(n0 + row) * EDIM + k0 + sc * 8, Bl + (j * 4 + wv) * 512);
    }
    __syncthreads();
#pragma unroll
    for (int kk = 0; kk < 2; ++kk) {
      short8 af[4], bf8[4];
#pragma unroll
      for (int i = 0; i < 4; ++i) {
        const int ra = wr * 64 + i * 16 + col;
        const int rb = wc * 64 + i * 16 + col;
        af[i]  = *(const short8*)(Al + ra * 64 + ((((kk << 2) + kg) ^ (ra & 7)) << 3));
        bf8[i] = *(const short8*)(Bl + rb * 64 + ((((kk << 2) + kg) ^ (rb & 7)) << 3));
      }
#pragma unroll
      for (int mi = 0; mi < 4; ++mi)
#pragma unroll
        for (int nj = 0; nj < 4; ++nj)
          acc[mi][nj] = __builtin_amdgcn_mfma_f32_16x16x32_bf16(af[mi], bf8[nj], acc[mi][nj], 0, 0, 0);
    }
  }

#pragma unroll
  for (int mi = 0; mi < 4; ++mi) {
#pragma unroll
    for (int j = 0; j < 4; ++j) {
      const size_t r = m0 + wr * 64 + mi * 16 + kg * 4 + j;
#pragma unroll
      for (int nj = 0; nj < 4; ++nj) {
        const int e = n0 + wc * 64 + nj * 16 + col;
        O[r * EDIM + e] = acc[mi][nj][j] + bv[e];
      }
    }
  }
}

// ---------------- host ----------------
extern "C" void kernel_launch(void* const* d_in, const int* in_sizes, int n_in,
                              void* d_out, int out_size, void* d_ws, size_t ws_size,
                              hipStream_t stream) {
  const float* state1 = (const float*)d_in[0];
  const float* state2 = (const float*)d_in[1];
  const float* Wq = (const float*)d_in[2];
  const float* bq = (const float*)d_in[3];
  const float* Wk = (const float*)d_in[4];
  // d_in[5] = bk: softmax-invariant -> unused
  const float* Wv = (const float*)d_in[6];
  const float* bv = (const float*)d_in[7];

  const size_t Mtot = (size_t)8 * 4096;
  float* out1 = (float*)d_out;
  float* out2 = out1 + Mtot * EDIM;

  // ws layout: Wvb | Hb | tvec | w1 | w2 | per-chunk {S1b, S2b, T1,T2,Y1,Y2}
  short* Wvb = (short*)d_ws;
  short* Hb = Wvb + WELEMS;
  float* tvec = (float*)(Hb + WELEMS);
  float* w1 = tvec + EDIM;
  float* w2 = w1 + Mtot;
  short* base = (short*)(w2 + Mtot);

  const size_t fixed_bytes = (size_t)(2 * WELEMS) * 2 + (EDIM + 2 * Mtot) * 4;
  size_t nch = 1;
  while (nch < 256) {
    size_t need = fixed_bytes + (size_t)6 * (Mtot / nch) * EDIM * 2;
    if (need <= ws_size) break;
    nch <<= 1;
  }
  const size_t Mc = Mtot / nch;
  const size_t McE = Mc * EDIM;
  const int mblocks = (int)(Mc / 128);
  short* S1b = base;
  short* S2b = S1b + McE;
  short* TV = S2b + McE;  // T1, T2, Y1, Y2

  prep<<<dim3(520), dim3(256), 0, stream>>>(Wq, bq, Wk, Wv, Wvb, tvec, Hb);

  for (size_t c = 0; c < nch; ++c) {
    const size_t roff = c * Mc;
    convert_x<<<dim3((unsigned)(Mc / 4)), dim3(256), 0, stream>>>(
        state1 + roff * EDIM, state2 + roff * EDIM, tvec, S1b, S2b, w1 + roff, w2 + roff);
    proj_t<<<dim3((unsigned)(mblocks * 8)), dim3(256), 0, stream>>>(
        S1b, S2b, Hb, TV, McE, mblocks);
    attn_y<<<dim3((unsigned)(Mc / 64), 2), dim3(256), 0, stream>>>(
        TV, S1b, S2b, w1 + roff, w2 + roff, McE);
    out_gemm<<<dim3((unsigned)(mblocks * 8)), dim3(256), 0, stream>>>(
        TV, Wvb, bv, out1 + roff * EDIM, out2 + roff * EDIM, McE, mblocks);
  }
}

// Round 10
// 183.891 us; speedup vs baseline: 1.8071x; 1.0883x over previous
//
#include <hip/hip_runtime.h>
#include <hip/hip_bf16.h>

typedef __attribute__((ext_vector_type(4))) float f32x4;
typedef __attribute__((ext_vector_type(8))) short short8;
typedef __attribute__((ext_vector_type(4))) short short4v;

#define EDIM 512
#define WELEMS 262144  // 512*512

static __device__ __forceinline__ short f2bf(float f) {
  union { float f; unsigned u; } v; v.f = f;
  unsigned r = v.u + 0x7fffu + ((v.u >> 16) & 1u);  // RNE
  return (short)(r >> 16);
}
static __device__ __forceinline__ float bf2f(short s) {
  union { float f; unsigned u; } v; v.u = ((unsigned)(unsigned short)s) << 16;
  return v.f;
}

// async global -> LDS, 16B per lane; lds base wave-uniform + lane*16 linear.
static __device__ __forceinline__ void gload_lds16(const short* g, short* l) {
  __builtin_amdgcn_global_load_lds(
      (const __attribute__((address_space(1))) unsigned int*)g,
      (__attribute__((address_space(3))) unsigned int*)(unsigned int)(unsigned long long)l,
      16, 0, 0);
}

// ---- merged prep + state convert, one dispatch ----
// blocks [0,256): Wv->bf16 | [256,264): tvec = Wk^T bq | [264,520): H = Wk^T Wq
// blocks [prep_blocks, ...): states fp32->bf16 (pure streaming; w-dot moved to attn)
__global__ __launch_bounds__(256) void prep_convert(
    const float* __restrict__ s1, const float* __restrict__ s2,
    const float* __restrict__ Wq, const float* __restrict__ bq,
    const float* __restrict__ Wk, const float* __restrict__ Wv,
    short* __restrict__ Wvb, float* __restrict__ tvec, short* __restrict__ Hb,
    short* __restrict__ o1, short* __restrict__ o2, int prep_blocks) {
  __shared__ float sh[2][64][33];
  const int b = blockIdx.x;
  const int tid = threadIdx.x;
  if (b < prep_blocks) {
    if (b < 256) {
      int i = (b * 256 + tid) * 4;
      f32x4 v = *(const f32x4*)(Wv + i);
      short4v vs;
#pragma unroll
      for (int j = 0; j < 4; ++j) vs[j] = f2bf(v[j]);
      *(short4v*)(Wvb + i) = vs;
    } else if (b < 264) {
      float* red = &sh[0][0][0];  // [4][64]
      const int fl = tid & 63;
      const int part = tid >> 6;
      const int f = (b - 256) * 64 + fl;
      float s = 0.f;
      const int n0 = part * 128;
#pragma unroll 8
      for (int n = n0; n < n0 + 128; ++n) s += Wk[(size_t)n * EDIM + f] * bq[n];
      red[part * 64 + fl] = s;
      __syncthreads();
      if (part == 0)
        tvec[f] = ((red[fl] + red[64 + fl]) + (red[128 + fl] + red[192 + fl]));
    } else {
      const int hb = b - 264;
      const int bf = (hb >> 4) * 32;
      const int be = (hb & 15) * 32;
      const int fh = (tid & 15) * 2;
      const int eh = (tid >> 4) * 2;
      float a00 = 0, a01 = 0, a10 = 0, a11 = 0;
      for (int nc = 0; nc < 8; ++nc) {
        __syncthreads();
#pragma unroll
        for (int p = 0; p < 8; ++p) {
          const int idx = p * 256 + tid;  // 2048 = 64n x 32f
          const int n = idx >> 5, f = idx & 31;
          sh[0][n][f] = Wk[(size_t)(nc * 64 + n) * EDIM + bf + f];
          sh[1][n][f] = Wq[(size_t)(nc * 64 + n) * EDIM + be + f];
        }
        __syncthreads();
#pragma unroll 4
        for (int n = 0; n < 64; ++n) {
          const float k0 = sh[0][n][fh], k1 = sh[0][n][fh + 1];
          const float q0 = sh[1][n][eh], q1 = sh[1][n][eh + 1];
          a00 += k0 * q0; a01 += k0 * q1; a10 += k1 * q0; a11 += k1 * q1;
        }
      }
      Hb[(size_t)(bf + fh) * EDIM + be + eh] = f2bf(a00);
      Hb[(size_t)(bf + fh) * EDIM + be + eh + 1] = f2bf(a01);
      Hb[(size_t)(bf + fh + 1) * EDIM + be + eh] = f2bf(a10);
      Hb[(size_t)(bf + fh + 1) * EDIM + be + eh + 1] = f2bf(a11);
    }
  } else {
    const int cb = b - prep_blocks;
    const int wv = tid >> 6, lane = tid & 63;
    const size_t r = (size_t)cb * 4 + wv;
    const int off = lane * 8;
#pragma unroll
    for (int st = 0; st < 2; ++st) {
      const float* src = st ? s2 : s1;
      f32x4 a0 = *(const f32x4*)(src + r * EDIM + off);
      f32x4 a1 = *(const f32x4*)(src + r * EDIM + off + 4);
      short8 rb;
#pragma unroll
      for (int j = 0; j < 4; ++j) { rb[j] = f2bf(a0[j]); rb[j + 4] = f2bf(a1[j]); }
      *(short8*)((st ? o2 : o1) + r * EDIM + off) = rb;
    }
  }
}

// ------- T GEMM (r7 structure): T_d = X_d @ H^T, bf16 out -------
// grid = mblocks*8: zn = 8 combos (2 dirs x 4 nb), XCD decode.
__global__ __launch_bounds__(256, 3) void proj_t(
    const short* __restrict__ S1b, const short* __restrict__ S2b,
    const short* __restrict__ Hb,
    short* __restrict__ TV, size_t McE, int mblocks) {
  __shared__ short Al[128 * 64];
  __shared__ short Bl[128 * 64];

  int mb, zn;
  {
    const int L = blockIdx.x;
    if ((mblocks & 7) == 0) {
      const int mpx = mblocks >> 3;
      const int xcd = L & 7;
      const int slot = L >> 3;
      mb = xcd * mpx + slot / 8;
      zn = slot % 8;
    } else { mb = L / 8; zn = L % 8; }
  }
  const int z = zn >> 2;   // dir
  const int nb = zn & 3;

  const short* __restrict__ X = z ? S2b : S1b;
  short* __restrict__ O = TV + (size_t)z * McE;

  const int m0 = mb * 128;
  const int n0 = nb * 128;
  const int tid = threadIdx.x;
  const int lane = tid & 63;
  const int wv = tid >> 6;
  const int wr = wv >> 1, wc = wv & 1;
  const int col = lane & 15;
  const int kg = lane >> 4;

  f32x4 acc[4][4] = {};

  for (int ks = 0; ks < EDIM / 64; ++ks) {
    const int k0 = ks * 64;
    __syncthreads();
#pragma unroll
    for (int j = 0; j < 4; ++j) {
      const int g = (j * 4 + wv) * 64 + lane;
      const int row = g >> 3;
      const int sc = (g & 7) ^ (row & 7);
      gload_lds16(X + (size_t)(m0 + row) * EDIM + k0 + sc * 8, Al + (j * 4 + wv) * 512);
      gload_lds16(Hb + (size_t)(n0 + row) * EDIM + k0 + sc * 8, Bl + (j * 4 + wv) * 512);
    }
    __syncthreads();
#pragma unroll
    for (int kk = 0; kk < 2; ++kk) {
      short8 af[4], bf8[4];
#pragma unroll
      for (int i = 0; i < 4; ++i) {
        const int ra = wr * 64 + i * 16 + col;
        const int rb = wc * 64 + i * 16 + col;
        af[i]  = *(const short8*)(Al + ra * 64 + ((((kk << 2) + kg) ^ (ra & 7)) << 3));
        bf8[i] = *(const short8*)(Bl + rb * 64 + ((((kk << 2) + kg) ^ (rb & 7)) << 3));
      }
#pragma unroll
      for (int mi = 0; mi < 4; ++mi)
#pragma unroll
        for (int nj = 0; nj < 4; ++nj)
          acc[mi][nj] = __builtin_amdgcn_mfma_f32_16x16x32_bf16(af[mi], bf8[nj], acc[mi][nj], 0, 0, 0);
    }
  }

#pragma unroll
  for (int mi = 0; mi < 4; ++mi) {
#pragma unroll
    for (int j = 0; j < 4; ++j) {
      const size_t r = m0 + wr * 64 + mi * 16 + kg * 4 + j;
#pragma unroll
      for (int nj = 0; nj < 4; ++nj) {
        const int e = n0 + wc * 64 + nj * 16 + col;
        O[r * EDIM + e] = f2bf(acc[mi][nj][j]);
      }
    }
  }
}

// ------- block attention -> Y = P @ X (bf16) -------
// S = T@X^T + w[k], w[k] = X[k]·tvec computed in-loop from the already-loaded
// K fragments (lane covers row r0+col, elems {ks*32+kg*8..+8}); kg-reduce via
// shfl_xor(16|32). V algebraically eliminated (out = (P@X)@Wv^T + bv).
__global__ __launch_bounds__(256) void attn_y(
    const short* __restrict__ TV, const short* __restrict__ S1b, const short* __restrict__ S2b,
    const float* __restrict__ tvec, size_t McE) {
  __shared__ float plds[4][16][16];
  const int dir = blockIdx.y;
  const short* __restrict__ Q = TV + (size_t)dir * McE;     // T1 : T2
  const short* __restrict__ KV = dir ? S1b : S2b;           // K and "V" are the same X
  short* __restrict__ Y = (short*)TV + (size_t)(2 + dir) * McE;

  const int lane = threadIdx.x & 63;
  const int wv = threadIdx.x >> 6;
  const size_t r0 = ((size_t)blockIdx.x * 4 + wv) * 16;
  const int col = lane & 15;
  const int kg = lane >> 4;

  const short* Qp = Q + (r0 + col) * EDIM + kg * 8;
  const short* Kp = KV + (r0 + col) * EDIM + kg * 8;
  f32x4 s = {};
  float wp = 0.f;
#pragma unroll
  for (int ks = 0; ks < 16; ++ks) {
    short8 a = *(const short8*)(Qp + ks * 32);
    short8 b = *(const short8*)(Kp + ks * 32);
    const f32x4 t0 = *(const f32x4*)(tvec + ks * 32 + kg * 8);
    const f32x4 t1 = *(const f32x4*)(tvec + ks * 32 + kg * 8 + 4);
#pragma unroll
    for (int i = 0; i < 4; ++i)
      wp += bf2f(b[i]) * t0[i] + bf2f(b[i + 4]) * t1[i];
    s = __builtin_amdgcn_mfma_f32_16x16x32_bf16(a, b, s, 0, 0, 0);
  }
  // sum w-partials across the 4 kg lanes sharing this K row
  wp += __shfl_xor(wp, 16);
  wp += __shfl_xor(wp, 32);

  const float scale = 0.04419417382415922f;  // 1/sqrt(512)
  float p[4];
#pragma unroll
  for (int j = 0; j < 4; ++j) p[j] = (s[j] + wp) * scale;
#pragma unroll
  for (int j = 0; j < 4; ++j) {
    float m = p[j];
#pragma unroll
    for (int d = 1; d < 16; d <<= 1) m = fmaxf(m, __shfl_xor(m, d));
    float e = __expf(p[j] - m);
    float ssum = e;
#pragma unroll
    for (int d = 1; d < 16; d <<= 1) ssum += __shfl_xor(ssum, d);
    p[j] = e / ssum;
  }
#pragma unroll
  for (int j = 0; j < 4; ++j) plds[wv][kg * 4 + j][col] = p[j];
  __syncthreads();

  const int e0 = lane * 8;
  short8 v8[16];
#pragma unroll
  for (int k = 0; k < 16; ++k) v8[k] = *(const short8*)(KV + (r0 + k) * EDIM + e0);
#pragma unroll
  for (int q = 0; q < 16; ++q) {
    float acc[8] = {0, 0, 0, 0, 0, 0, 0, 0};
#pragma unroll
    for (int k = 0; k < 16; ++k) {
      const float pv = plds[wv][q][k];
#pragma unroll
      for (int i = 0; i < 8; ++i) acc[i] += pv * bf2f(v8[k][i]);
    }
    short8 y;
#pragma unroll
    for (int i = 0; i < 8; ++i) y[i] = f2bf(acc[i]);
    *(short8*)(Y + (r0 + q) * EDIM + e0) = y;
  }
}

// ------- out GEMM (r7 structure): out_d = Y_d @ Wv^T + bv, fp32 out -------
__global__ __launch_bounds__(256, 3) void out_gemm(
    const short* __restrict__ TV, const short* __restrict__ Wvb,
    const float* __restrict__ bv,
    float* __restrict__ out1, float* __restrict__ out2, size_t McE, int mblocks) {
  __shared__ short Al[128 * 64];
  __shared__ short Bl[128 * 64];

  int mb, zn;
  {
    const int L = blockIdx.x;
    if ((mblocks & 7) == 0) {
      const int mpx = mblocks >> 3;
      const int xcd = L & 7;
      const int slot = L >> 3;
      mb = xcd * mpx + slot / 8;
      zn = slot % 8;
    } else { mb = L / 8; zn = L % 8; }
  }
  const int z = zn >> 2;   // dir
  const int nb = zn & 3;

  const short* __restrict__ A = TV + (size_t)(2 + z) * McE;  // Y1 : Y2
  float* __restrict__ O = z ? out2 : out1;

  const int m0 = mb * 128;
  const int n0 = nb * 128;
  const int tid = threadIdx.x;
  const int lane = tid & 63;
  const int wv = tid >> 6;
  const int wr = wv >> 1, wc = wv & 1;
  const int col = lane & 15;
  const int kg = lane >> 4;

  f32x4 acc[4][4] = {};

  for (int ks = 0; ks < EDIM / 64; ++ks) {
    const int k0 = ks * 64;
    __syncthreads();
#pragma unroll
    for (int j = 0; j < 4; ++j) {
      const int g = (j * 4 + wv) * 64 + lane;
      const int row = g >> 3;
      const int sc = (g & 7) ^ (row & 7);
      gload_lds16(A + (size_t)(m0 + row) * EDIM + k0 + sc * 8, Al + (j * 4 + wv) * 512);
      gload_lds16(Wvb + (size_t)(n0 + row) * EDIM + k0 + sc * 8, Bl + (j * 4 + wv) * 512);
    }
    __syncthreads();
#pragma unroll
    for (int kk = 0; kk < 2; ++kk) {
      short8 af[4], bf8[4];
#pragma unroll
      for (int i = 0; i < 4; ++i) {
        const int ra = wr * 64 + i * 16 + col;
        const int rb = wc * 64 + i * 16 + col;
        af[i]  = *(const short8*)(Al + ra * 64 + ((((kk << 2) + kg) ^ (ra & 7)) << 3));
        bf8[i] = *(const short8*)(Bl + rb * 64 + ((((kk << 2) + kg) ^ (rb & 7)) << 3));
      }
#pragma unroll
      for (int mi = 0; mi < 4; ++mi)
#pragma unroll
        for (int nj = 0; nj < 4; ++nj)
          acc[mi][nj] = __builtin_amdgcn_mfma_f32_16x16x32_bf16(af[mi], bf8[nj], acc[mi][nj], 0, 0, 0);
    }
  }

#pragma unroll
  for (int mi = 0; mi < 4; ++mi) {
#pragma unroll
    for (int j = 0; j < 4; ++j) {
      const size_t r = m0 + wr * 64 + mi * 16 + kg * 4 + j;
#pragma unroll
      for (int nj = 0; nj < 4; ++nj) {
        const int e = n0 + wc * 64 + nj * 16 + col;
        O[r * EDIM + e] = acc[mi][nj][j] + bv[e];
      }
    }
  }
}

// ---------------- host ----------------
extern "C" void kernel_launch(void* const* d_in, const int* in_sizes, int n_in,
                              void* d_out, int out_size, void* d_ws, size_t ws_size,
                              hipStream_t stream) {
  const float* state1 = (const float*)d_in[0];
  const float* state2 = (const float*)d_in[1];
  const float* Wq = (const float*)d_in[2];
  const float* bq = (const float*)d_in[3];
  const float* Wk = (const float*)d_in[4];
  // d_in[5] = bk: softmax-invariant -> unused
  const float* Wv = (const float*)d_in[6];
  const float* bv = (const float*)d_in[7];

  const size_t Mtot = (size_t)8 * 4096;
  float* out1 = (float*)d_out;
  float* out2 = out1 + Mtot * EDIM;

  // ws layout: Wvb | Hb | tvec | per-chunk {S1b, S2b, T1,T2,Y1,Y2}
  short* Wvb = (short*)d_ws;
  short* Hb = Wvb + WELEMS;
  float* tvec = (float*)(Hb + WELEMS);
  short* base = (short*)(tvec + EDIM);

  const size_t fixed_bytes = (size_t)(2 * WELEMS) * 2 + EDIM * 4;
  size_t nch = 1;
  while (nch < 256) {
    size_t need = fixed_bytes + (size_t)6 * (Mtot / nch) * EDIM * 2;
    if (need <= ws_size) break;
    nch <<= 1;
  }
  const size_t Mc = Mtot / nch;
  const size_t McE = Mc * EDIM;
  const int mblocks = (int)(Mc / 128);
  short* S1b = base;
  short* S2b = S1b + McE;
  short* TV = S2b + McE;  // T1, T2, Y1, Y2

  for (size_t c = 0; c < nch; ++c) {
    const size_t roff = c * Mc;
    const int pb = (c == 0) ? 520 : 0;  // prep only on first chunk
    prep_convert<<<dim3((unsigned)(Mc / 4 + pb)), dim3(256), 0, stream>>>(
        state1 + roff * EDIM, state2 + roff * EDIM, Wq, bq, Wk, Wv,
        Wvb, tvec, Hb, S1b, S2b, pb);
    proj_t<<<dim3((unsigned)(mblocks * 8)), dim3(256), 0, stream>>>(
        S1b, S2b, Hb, TV, McE, mblocks);
    attn_y<<<dim3((unsigned)(Mc / 64), 2), dim3(256), 0, stream>>>(
        TV, S1b, S2b, tvec, McE);
    out_gemm<<<dim3((unsigned)(mblocks * 8)), dim3(256), 0, stream>>>(
        TV, Wvb, bv, out1 + roff * EDIM, out2 + roff * EDIM, McE, mblocks);
  }
}